// Round 11
// baseline (68.791 us; speedup 1.0000x reference)
//
#include <hip/hip_runtime.h>

#define NBATCH 4096
#define NNODE  32
#define NVOCAB 100
#define DIM    64
#define EPG    512
#define HSTR   68      // padded fp32 LDS row stride
#define LN_EPS 1e-5f
#define CDIM   192
#define C2DIM  384

// workspace layout (bytes)
#define WS_WFRAG_OFF   0         // 3 x 16384 B stage-W frags (Win1, Win2@Wh1, Wh2@Wh1)
#define WS_B21_OFF     49152     // 128 floats: b21a(64), b21b(64)
#define WS_WCF_OFF     65536     // Wc_eff frags: hi 147456 + lo 147456
#define WS_BCE_OFF     360448    // bc_eff: 384 floats
#define WS_POOL_OFF    364544    // cs 4096*192 f32

typedef float          f32x4  __attribute__((ext_vector_type(4)));
typedef unsigned int   u32x4  __attribute__((ext_vector_type(4)));
typedef __bf16         bf16x8 __attribute__((ext_vector_type(8)));

__device__ __forceinline__ float4 ldg4(const float* __restrict__ p) {
    return *reinterpret_cast<const float4*>(p);
}
__device__ __forceinline__ unsigned short f2bf(float f) {
    return __builtin_bit_cast(unsigned short, static_cast<__bf16>(f));
}
__device__ __forceinline__ float bf2f(unsigned short h) {
    return static_cast<float>(__builtin_bit_cast(__bf16, h));
}
__device__ __forceinline__ unsigned int pk2(float a, float b) {
    return (unsigned int)f2bf(a) | ((unsigned int)f2bf(b) << 16);
}
__device__ __forceinline__ unsigned int pk2lo(float a, float b, unsigned int hi) {
    const float ra = a - bf2f((unsigned short)(hi & 0xffff));
    const float rb = b - bf2f((unsigned short)(hi >> 16));
    return pk2(ra, rb);
}
__device__ __forceinline__ bf16x8 as_bf(u32x4 v) {
    return __builtin_bit_cast(bf16x8, v);
}
#define MFMA(a, b, c) __builtin_amdgcn_mfma_f32_16x16x32_bf16(as_bf(a), as_bf(b), (c), 0, 0, 0)

// ---- pre-kernel (unchanged from round 9) ----
extern "C" __global__ void __launch_bounds__(256)
prep_w_kernel(const float* __restrict__ win1, const float* __restrict__ win2,
              const float* __restrict__ wh1,  const float* __restrict__ wh2,
              const float* __restrict__ wc1,  const float* __restrict__ bin2,
              const float* __restrict__ bh2,  const float* __restrict__ bc1,
              unsigned short* __restrict__ wsb, unsigned short* __restrict__ wcf,
              float* __restrict__ b21, float* __restrict__ bce)
{
    __shared__ float sh[14400];
    const int blk = blockIdx.x, t = threadIdx.x;

    if (blk < 3) {
        float* C = sh + 4096;
        if (blk == 0) {
            for (int i = t; i < 1024; i += 256)
                *(float4*)&C[i * 4] = ldg4(win1 + i * 4);
            __syncthreads();
        } else {
            const float* A2 = (blk == 1) ? win2 : wh2;
            const float* bb = (blk == 1) ? bin2 : bh2;
            float* Bm    = sh;
            float* A2lds = sh + 8192;
            for (int i = t; i < 1024; i += 256)
                *(float4*)&Bm[i * 4] = ldg4(wh1 + i * 4);
            for (int i = t; i < 4096; i += 256) {
                const int r = i >> 6, k = i & 63;
                A2lds[r * 65 + k] = A2[i];
            }
            __syncthreads();
            const int r = t >> 2, cb = (t & 3) * 16;
            float av[16];
            #pragma unroll
            for (int c = 0; c < 16; ++c) av[c] = 0.f;
            for (int k = 0; k < 64; ++k) {
                const float a = A2lds[r * 65 + k];
                const float4 w0 = *(const float4*)&Bm[k * 64 + cb];
                const float4 w1 = *(const float4*)&Bm[k * 64 + cb + 4];
                const float4 w2 = *(const float4*)&Bm[k * 64 + cb + 8];
                const float4 w3 = *(const float4*)&Bm[k * 64 + cb + 12];
                av[0]=fmaf(a,w0.x,av[0]); av[1]=fmaf(a,w0.y,av[1]); av[2]=fmaf(a,w0.z,av[2]); av[3]=fmaf(a,w0.w,av[3]);
                av[4]=fmaf(a,w1.x,av[4]); av[5]=fmaf(a,w1.y,av[5]); av[6]=fmaf(a,w1.z,av[6]); av[7]=fmaf(a,w1.w,av[7]);
                av[8]=fmaf(a,w2.x,av[8]); av[9]=fmaf(a,w2.y,av[9]); av[10]=fmaf(a,w2.z,av[10]); av[11]=fmaf(a,w2.w,av[11]);
                av[12]=fmaf(a,w3.x,av[12]); av[13]=fmaf(a,w3.y,av[13]); av[14]=fmaf(a,w3.z,av[14]); av[15]=fmaf(a,w3.w,av[15]);
            }
            #pragma unroll
            for (int c = 0; c < 16; ++c) C[r * 64 + cb + c] = av[c];
            if (t < 64) {
                float s = 0.f;
                for (int k = 0; k < 64; ++k) s = fmaf(bb[k], Bm[k * 64 + t], s);
                b21[(blk - 1) * 64 + t] = s;
            }
            __syncthreads();
        }
        unsigned short* hi = wsb + blk * 8192;
        unsigned short* lo = hi + 4096;
        for (int f = t; f < 512; f += 256) {
            const int s = f >> 8, n = (f >> 6) & 3, ll = f & 63;
            const int g = ll >> 4, col = n * 16 + (ll & 15);
            unsigned int uh[4], ul[4];
            #pragma unroll
            for (int j2 = 0; j2 < 4; ++j2) {
                const float a  = C[(s * 32 + g * 8 + j2 * 2)     * 64 + col];
                const float bq = C[(s * 32 + g * 8 + j2 * 2 + 1) * 64 + col];
                uh[j2] = pk2(a, bq);
                ul[j2] = pk2lo(a, bq, uh[j2]);
            }
            *(u32x4*)(hi + f * 8) = (u32x4){uh[0], uh[1], uh[2], uh[3]};
            *(u32x4*)(lo + f * 8) = (u32x4){ul[0], ul[1], ul[2], ul[3]};
        }
    } else if (blk < 15) {
        const int chunk = blk - 3;
        float* wc1c = sh;
        float* A2T  = sh + 6144;
        for (int i = t; i < 1536; i += 256) {
            const int row = i >> 3, q = i & 7;
            *(float4*)&wc1c[row * 32 + q * 4] = ldg4(wc1 + (size_t)row * C2DIM + chunk * 32 + q * 4);
        }
        for (int i = t; i < 8192; i += 256) {
            const int r = i >> 6, k = i & 63;
            const float v = (r < 64) ? win2[r * 64 + k] : wh2[(r - 64) * 64 + k];
            A2T[k * 129 + r] = v;
        }
        __syncthreads();
        float acc[32];
        if (t < 192) {
            const int R  = (t < 64) ? t : 64 + (t & 63);
            const int kb = (t >> 6) * 64;
            #pragma unroll
            for (int c = 0; c < 32; ++c) acc[c] = 0.f;
            for (int k = 0; k < 64; ++k) {
                const float a = A2T[k * 129 + R];
                const float* wr = &wc1c[(kb + k) * 32];
                #pragma unroll
                for (int c4 = 0; c4 < 8; ++c4) {
                    const float4 w = *(const float4*)&wr[c4 * 4];
                    acc[c4 * 4 + 0] = fmaf(a, w.x, acc[c4 * 4 + 0]);
                    acc[c4 * 4 + 1] = fmaf(a, w.y, acc[c4 * 4 + 1]);
                    acc[c4 * 4 + 2] = fmaf(a, w.z, acc[c4 * 4 + 2]);
                    acc[c4 * 4 + 3] = fmaf(a, w.w, acc[c4 * 4 + 3]);
                }
            }
        }
        __syncthreads();
        float* C2 = sh;
        if (t < 192) {
            #pragma unroll
            for (int c = 0; c < 32; ++c) C2[t * 33 + c] = acc[c];
        }
        __syncthreads();
        unsigned short* hi = wcf;
        unsigned short* lo = wcf + 73728;
        for (int i = t; i < 768; i += 256) {
            const int s = i / 128, rem = i % 128;
            const int nl = rem >> 6, ll = rem & 63;
            const int n = chunk * 2 + nl;
            const int e = (s * 24 + n) * 64 + ll;
            const int cl = nl * 16 + (ll & 15);
            const int k0 = s * 32 + (ll >> 4) * 8;
            unsigned int uh[4], ul[4];
            #pragma unroll
            for (int j2 = 0; j2 < 4; ++j2) {
                const float a  = C2[(k0 + j2 * 2)     * 33 + cl];
                const float bq = C2[(k0 + j2 * 2 + 1) * 33 + cl];
                uh[j2] = pk2(a, bq);
                ul[j2] = pk2lo(a, bq, uh[j2]);
            }
            *(u32x4*)(hi + e * 8) = (u32x4){uh[0], uh[1], uh[2], uh[3]};
            *(u32x4*)(lo + e * 8) = (u32x4){ul[0], ul[1], ul[2], ul[3]};
        }
    } else {
        for (int j = t; j < C2DIM; j += 256) {
            float s = 0.f;
            for (int k = 0; k < 64; ++k) {
                s = fmaf(bin2[k], wc1[(size_t)k * C2DIM + j], s);
                s = fmaf(bh2[k],  wc1[(size_t)(64 + k) * C2DIM + j], s);
                s = fmaf(bh2[k],  wc1[(size_t)(128 + k) * C2DIM + j], s);
            }
            bce[j] = bc1[j] + 32.0f * s;
        }
    }
}

// ==== main kernel: one BLOCK (2 waves) = one graph; wave w owns m-tile w ====
extern "C" __global__ void __launch_bounds__(128, 8)
gin_fused_kernel(const int* __restrict__ x, const int* __restrict__ los,
                 const int* __restrict__ eidx,
                 const float* __restrict__ emb,
                 const float* __restrict__ bin1,
                 const float* __restrict__ gin_g, const float* __restrict__ gin_b,
                 const float* __restrict__ bh1,
                 const float* __restrict__ gh_g, const float* __restrict__ gh_b,
                 const float* __restrict__ epsv,
                 const unsigned short* __restrict__ wsb,
                 const float* __restrict__ b21,
                 float* __restrict__ pooled_ws)
{
    __shared__ __align__(16) float scr[NNODE * HSTR];   // 8704 B shared state
    __shared__ float pcs[2][64];                        // colsum partials

    const int t  = threadIdx.x;
    const int w  = t >> 6;          // wave id = m-tile
    const int l  = t & 63;
    const int b  = blockIdx.x;
    const int lc = l & 15;
    const int lg = l >> 4;

    // ---- histogram (block-shared; cnt aliases scr) ----
    int* cnt = (int*)scr;
    #pragma unroll
    for (int i = 0; i < 8; ++i) cnt[t + 128 * i] = 0;
    __syncthreads();
    {
        const int ebase = b * EPG;
        const int goff  = b * NNODE;
        #pragma unroll
        for (int i = 0; i < 4; ++i) {
            const int e = ebase + t + 128 * i;
            const int sN = eidx[e] - goff;
            const int dN = eidx[NBATCH * EPG + e] - goff;
            atomicAdd(&cnt[dN * NNODE + sN], 1);
        }
    }
    __syncthreads();
    // ---- adjacency A-frag for this wave's m-tile (counts exact in bf16) ----
    u32x4 adjf;
    {
        const int rowA = w * 16 + lc;
        const int4 a0 = *(const int4*)&cnt[rowA * NNODE + lg * 8];
        const int4 a1 = *(const int4*)&cnt[rowA * NNODE + lg * 8 + 4];
        adjf = (u32x4){ pk2((float)a0.x, (float)a0.y), pk2((float)a0.z, (float)a0.w),
                        pk2((float)a1.x, (float)a1.y), pk2((float)a1.z, (float)a1.w) };
    }
    __syncthreads();   // cnt reads done before emb overwrite (cross-wave WAR)
    // ---- embedding -> scr: thread t loads node t>>2 (wave w -> own rows) ----
    {
        const int node = t >> 2;
        const int q = (t & 3) * 16;
        const int idx = (node < NNODE - 1) ? x[b * (NNODE - 1) + node] : los[b];
        const float* er = emb + ((size_t)(node * NVOCAB + idx)) * DIM + q;
        float* sr = scr + node * HSTR + q;
        #pragma unroll
        for (int i = 0; i < 4; ++i)
            *reinterpret_cast<float4*>(sr + i * 4) = ldg4(er + i * 4);
    }
    // (no barrier: wave w wrote exactly its own rows; st0 A-frag reads own rows)

    f32x4 acc[4];                    // this wave's 16x64 C-slice
    u32x4 azh[2], azl[2];

    for (int st = 0; st < 3; ++st) {
        const unsigned short* Wf = wsb + st * 8192;
        const float* bpost = st ? bh1  : bin1;
        const float* Gg    = st ? gh_g : gin_g;
        const float* Gb    = st ? gh_b : gin_b;
        const float sc = 1.0f + epsv[st];

        // stage input -> scr (own rows; stage0: embeddings already there)
        // (prev stage's colsum barrier guarantees all agg B-reads are done)
        if (st) {
            #pragma unroll
            for (int n = 0; n < 4; ++n)
                #pragma unroll
                for (int r = 0; r < 4; ++r)
                    scr[(w * 16 + lg * 4 + r) * HSTR + n * 16 + lc] = acc[n][r];
        }
        // A-frags of input (own rows; in-wave lgkmcnt ordering)
        #pragma unroll
        for (int s = 0; s < 2; ++s) {
            const float4 v0 = *(const float4*)&scr[(w * 16 + lc) * HSTR + s * 32 + lg * 8];
            const float4 v1 = *(const float4*)&scr[(w * 16 + lc) * HSTR + s * 32 + lg * 8 + 4];
            azh[s] = (u32x4){ pk2(v0.x,v0.y), pk2(v0.z,v0.w), pk2(v1.x,v1.y), pk2(v1.z,v1.w) };
            azl[s] = (u32x4){ pk2lo(v0.x,v0.y,azh[s][0]), pk2lo(v0.z,v0.w,azh[s][1]),
                              pk2lo(v1.x,v1.y,azh[s][2]), pk2lo(v1.z,v1.w,azh[s][3]) };
        }
        // v = input @ W + b_pre
        #pragma unroll
        for (int n = 0; n < 4; ++n) {
            const float bp = st ? b21[(st - 1) * 64 + n * 16 + lc] : 0.f;
            acc[n] = (f32x4){bp, bp, bp, bp};
        }
        #pragma unroll
        for (int n = 0; n < 4; ++n)
            #pragma unroll
            for (int s = 0; s < 2; ++s) {
                const u32x4 wh = *(const u32x4*)(Wf +        ((s * 4 + n) * 64 + l) * 8);
                const u32x4 wl = *(const u32x4*)(Wf + 4096 + ((s * 4 + n) * 64 + l) * 8);
                acc[n] = MFMA(azh[s], wh, acc[n]);
                acc[n] = MFMA(azh[s], wl, acc[n]);
                acc[n] = MFMA(azl[s], wh, acc[n]);
            }
        // v -> scr (own rows)
        #pragma unroll
        for (int n = 0; n < 4; ++n)
            #pragma unroll
            for (int r = 0; r < 4; ++r)
                scr[(w * 16 + lg * 4 + r) * HSTR + n * 16 + lc] = acc[n][r];
        // in-place seeds: acc = sc*v + b_post
        #pragma unroll
        for (int n = 0; n < 4; ++n) {
            const float bq = bpost[n * 16 + lc];
            #pragma unroll
            for (int r = 0; r < 4; ++r)
                acc[n][r] = sc * acc[n][r] + bq;
        }
        __syncthreads();   // all 32 v-rows visible for agg B-frags
        // agg: acc += A_adj(m=w) @ v  (B-frags span all 32 src nodes)
        #pragma unroll
        for (int n = 0; n < 4; ++n) {
            float h[8];
            #pragma unroll
            for (int j = 0; j < 8; ++j) h[j] = scr[(lg * 8 + j) * HSTR + n * 16 + lc];
            const u32x4 hh = (u32x4){ pk2(h[0],h[1]), pk2(h[2],h[3]), pk2(h[4],h[5]), pk2(h[6],h[7]) };
            const u32x4 hl = (u32x4){ pk2lo(h[0],h[1],hh[0]), pk2lo(h[2],h[3],hh[1]),
                                      pk2lo(h[4],h[5],hh[2]), pk2lo(h[6],h[7],hh[3]) };
            acc[n] = MFMA(adjf, hh, acc[n]);
            acc[n] = MFMA(adjf, hl, acc[n]);
        }
        // LayerNorm + relu (in-register; this wave's 16 rows)
        {
            float gg[4], gb[4];
            #pragma unroll
            for (int n = 0; n < 4; ++n) { gg[n] = Gg[n * 16 + lc]; gb[n] = Gb[n * 16 + lc]; }
            #pragma unroll
            for (int r = 0; r < 4; ++r) {
                float a0 = acc[0][r], a1 = acc[1][r];
                float a2 = acc[2][r], a3 = acc[3][r];
                float s1 = a0 + a1 + a2 + a3;
                float s2 = a0 * a0 + a1 * a1 + a2 * a2 + a3 * a3;
                s1 += __shfl_xor(s1, 1); s1 += __shfl_xor(s1, 2);
                s1 += __shfl_xor(s1, 4); s1 += __shfl_xor(s1, 8);
                s2 += __shfl_xor(s2, 1); s2 += __shfl_xor(s2, 2);
                s2 += __shfl_xor(s2, 4); s2 += __shfl_xor(s2, 8);
                const float mu  = s1 * (1.0f / 64.0f);
                const float var = s2 * (1.0f / 64.0f) - mu * mu;
                const float inv = rsqrtf(var + LN_EPS);
                acc[0][r] = fmaxf((a0 - mu) * inv * gg[0] + gb[0], 0.f);
                acc[1][r] = fmaxf((a1 - mu) * inv * gg[1] + gb[1], 0.f);
                acc[2][r] = fmaxf((a2 - mu) * inv * gg[2] + gb[2], 0.f);
                acc[3][r] = fmaxf((a3 - mu) * inv * gg[3] + gb[3], 0.f);
            }
        }
        // colsum partial (this wave's 16 rows) -> pcs; merge across waves
        #pragma unroll
        for (int n = 0; n < 4; ++n) {
            float p = acc[n][0] + acc[n][1] + acc[n][2] + acc[n][3];
            p += __shfl_xor(p, 16);
            p += __shfl_xor(p, 32);
            if (l < 16) pcs[w][n * 16 + l] = p;
        }
        __syncthreads();
        if (t < 64)
            pooled_ws[(size_t)b * CDIM + st * DIM + t] = pcs[0][t] + pcs[1][t];
    }
}

// ---- classifier: out = relu(cs @ Wc_eff + bc_eff) @ wc2 + bc2 (unchanged) ----
extern "C" __global__ void __launch_bounds__(256)
classifier_kernel(const float* __restrict__ pooled_ws,
                  const unsigned short* __restrict__ wcf,
                  const float* __restrict__ bce, const float* __restrict__ wc2,
                  const float* __restrict__ bc2, float* __restrict__ out)
{
    #define PSTR 196
    __shared__ __align__(16) float P[16 * PSTR];
    __shared__ __align__(16) unsigned int afh[6 * 64 * 4];
    __shared__ __align__(16) unsigned int afl[6 * 64 * 4];
    __shared__ float rsum[4][16];

    const int b = blockIdx.x;
    const int t = threadIdx.x;
    const int l = t & 63;
    const int w = t >> 6;
    const unsigned short* wclo = wcf + 73728;

    for (int i = t; i < 16 * 48; i += 256) {
        const int row = i / 48, q = i % 48;
        const float4 v = ldg4(pooled_ws + ((size_t)(b * 16 + row)) * CDIM + q * 4);
        *reinterpret_cast<float4*>(&P[row * PSTR + q * 4]) = v;
    }
    __syncthreads();

    for (int e = t; e < 6 * 64; e += 256) {
        const int s = e >> 6, ll = e & 63;
        const int row = ll & 15;
        const int k0 = s * 32 + (ll >> 4) * 8;
        const float4 v0 = *reinterpret_cast<const float4*>(&P[row * PSTR + k0]);
        const float4 v1 = *reinterpret_cast<const float4*>(&P[row * PSTR + k0 + 4]);
        const float y[8] = { v0.x, v0.y, v0.z, v0.w, v1.x, v1.y, v1.z, v1.w };
        unsigned int uh[4], ul[4];
        #pragma unroll
        for (int j2 = 0; j2 < 4; ++j2) {
            uh[j2] = pk2(y[j2 * 2], y[j2 * 2 + 1]);
            ul[j2] = pk2lo(y[j2 * 2], y[j2 * 2 + 1], uh[j2]);
        }
        *reinterpret_cast<u32x4*>(&afh[e * 4]) = (u32x4){uh[0], uh[1], uh[2], uh[3]};
        *reinterpret_cast<u32x4*>(&afl[e * 4]) = (u32x4){ul[0], ul[1], ul[2], ul[3]};
    }
    __syncthreads();

    float part[4] = {0.f, 0.f, 0.f, 0.f};
    for (int nt = 0; nt < 6; ++nt) {
        const int n = w * 6 + nt;
        f32x4 acc = {0.f, 0.f, 0.f, 0.f};
        #pragma unroll
        for (int s = 0; s < 6; ++s) {
            const u32x4 ah = *(const u32x4*)&afh[(s * 64 + l) * 4];
            const u32x4 al = *(const u32x4*)&afl[(s * 64 + l) * 4];
            const u32x4 bh = *(const u32x4*)&wcf [((s * 24 + n) * 64 + l) * 8];
            const u32x4 bl = *(const u32x4*)&wclo[((s * 24 + n) * 64 + l) * 8];
            acc = MFMA(ah, bh, acc);
            acc = MFMA(ah, bl, acc);
            acc = MFMA(al, bh, acc);
        }
        const int col = n * 16 + (l & 15);
        const float bias = bce[col], w2 = wc2[col];
        #pragma unroll
        for (int r = 0; r < 4; ++r)
            part[r] += fmaxf(acc[r] + bias, 0.f) * w2;
    }
    #pragma unroll
    for (int r = 0; r < 4; ++r) {
        part[r] += __shfl_xor(part[r], 1);
        part[r] += __shfl_xor(part[r], 2);
        part[r] += __shfl_xor(part[r], 4);
        part[r] += __shfl_xor(part[r], 8);
    }
    if ((l & 15) == 0) {
        const int g = l >> 4;
        #pragma unroll
        for (int r = 0; r < 4; ++r) rsum[w][g * 4 + r] = part[r];
    }
    __syncthreads();
    if (t < 16)
        out[b * 16 + t] = rsum[0][t] + rsum[1][t] + rsum[2][t] + rsum[3][t] + bc2[0];
}

extern "C" void kernel_launch(void* const* d_in, const int* in_sizes, int n_in,
                              void* d_out, int out_size, void* d_ws, size_t ws_size,
                              hipStream_t stream)
{
    const int*   x     = (const int*)d_in[0];
    const int*   los   = (const int*)d_in[1];
    const int*   eidx  = (const int*)d_in[2];
    const float* emb   = (const float*)d_in[3];
    const float* win1  = (const float*)d_in[4];
    const float* bin1  = (const float*)d_in[5];
    const float* gin_g = (const float*)d_in[6];
    const float* gin_b = (const float*)d_in[7];
    const float* win2  = (const float*)d_in[8];
    const float* bin2  = (const float*)d_in[9];
    const float* wh1   = (const float*)d_in[10];
    const float* bh1   = (const float*)d_in[11];
    const float* gh_g  = (const float*)d_in[12];
    const float* gh_b  = (const float*)d_in[13];
    const float* wh2   = (const float*)d_in[14];
    const float* bh2   = (const float*)d_in[15];
    const float* epsv  = (const float*)d_in[16];
    const float* wc1   = (const float*)d_in[17];
    const float* bc1   = (const float*)d_in[18];
    const float* wc2   = (const float*)d_in[19];
    const float* bc2   = (const float*)d_in[20];
    float* out = (float*)d_out;

    unsigned short* wsb = (unsigned short*)((char*)d_ws + WS_WFRAG_OFF);
    float*          b21 = (float*)((char*)d_ws + WS_B21_OFF);
    unsigned short* wcf = (unsigned short*)((char*)d_ws + WS_WCF_OFF);
    float*          bce = (float*)((char*)d_ws + WS_BCE_OFF);
    float*          cs  = (float*)((char*)d_ws + WS_POOL_OFF);

    hipLaunchKernelGGL(prep_w_kernel, dim3(16), dim3(256), 0, stream,
                       win1, win2, wh1, wh2, wc1, bin2, bh2, bc1,
                       wsb, wcf, b21, bce);
    hipLaunchKernelGGL(gin_fused_kernel, dim3(NBATCH), dim3(128), 0, stream,
                       x, los, eidx, emb, bin1, gin_g, gin_b,
                       bh1, gh_g, gh_b, epsv,
                       (const unsigned short*)wsb, (const float*)b21, cs);
    hipLaunchKernelGGL(classifier_kernel, dim3(NBATCH / 16), dim3(256), 0, stream,
                       (const float*)cs, (const unsigned short*)wcf,
                       (const float*)bce, wc2, bc2, out);
}

// Round 12
// 65.700 us; speedup vs baseline: 1.0471x; 1.0471x over previous
//
#include <hip/hip_runtime.h>

#define NBATCH 4096
#define NNODE  32
#define NVOCAB 100
#define DIM    64
#define EPG    512
#define HSTR   68      // padded fp32 LDS row stride
#define LN_EPS 1e-5f
#define CDIM   192
#define C2DIM  384

// workspace layout (bytes)
#define WS_WFRAG_OFF   0         // 3 x 16384 B stage-W frags (Win1, Win2@Wh1, Wh2@Wh1)
#define WS_B21_OFF     49152     // 128 floats: b21a(64), b21b(64)
#define WS_WCF_OFF     65536     // Wc_eff frags: hi 147456 + lo 147456
#define WS_BCE_OFF     360448    // bc_eff: 384 floats
#define WS_POOL_OFF    364544    // cs 4096*192 f32

typedef float          f32x4  __attribute__((ext_vector_type(4)));
typedef unsigned int   u32x4  __attribute__((ext_vector_type(4)));
typedef __bf16         bf16x8 __attribute__((ext_vector_type(8)));

__device__ __forceinline__ float4 ldg4(const float* __restrict__ p) {
    return *reinterpret_cast<const float4*>(p);
}
__device__ __forceinline__ unsigned short f2bf(float f) {
    return __builtin_bit_cast(unsigned short, static_cast<__bf16>(f));
}
__device__ __forceinline__ float bf2f(unsigned short h) {
    return static_cast<float>(__builtin_bit_cast(__bf16, h));
}
__device__ __forceinline__ unsigned int pk2(float a, float b) {
    return (unsigned int)f2bf(a) | ((unsigned int)f2bf(b) << 16);
}
__device__ __forceinline__ unsigned int pk2lo(float a, float b, unsigned int hi) {
    const float ra = a - bf2f((unsigned short)(hi & 0xffff));
    const float rb = b - bf2f((unsigned short)(hi >> 16));
    return pk2(ra, rb);
}
__device__ __forceinline__ bf16x8 as_bf(u32x4 v) {
    return __builtin_bit_cast(bf16x8, v);
}
#define MFMA(a, b, c) __builtin_amdgcn_mfma_f32_16x16x32_bf16(as_bf(a), as_bf(b), (c), 0, 0, 0)

// ---- pre-kernel (unchanged) ----
extern "C" __global__ void __launch_bounds__(256)
prep_w_kernel(const float* __restrict__ win1, const float* __restrict__ win2,
              const float* __restrict__ wh1,  const float* __restrict__ wh2,
              const float* __restrict__ wc1,  const float* __restrict__ bin2,
              const float* __restrict__ bh2,  const float* __restrict__ bc1,
              unsigned short* __restrict__ wsb, unsigned short* __restrict__ wcf,
              float* __restrict__ b21, float* __restrict__ bce)
{
    __shared__ float sh[14400];
    const int blk = blockIdx.x, t = threadIdx.x;

    if (blk < 3) {
        float* C = sh + 4096;
        if (blk == 0) {
            for (int i = t; i < 1024; i += 256)
                *(float4*)&C[i * 4] = ldg4(win1 + i * 4);
            __syncthreads();
        } else {
            const float* A2 = (blk == 1) ? win2 : wh2;
            const float* bb = (blk == 1) ? bin2 : bh2;
            float* Bm    = sh;
            float* A2lds = sh + 8192;
            for (int i = t; i < 1024; i += 256)
                *(float4*)&Bm[i * 4] = ldg4(wh1 + i * 4);
            for (int i = t; i < 4096; i += 256) {
                const int r = i >> 6, k = i & 63;
                A2lds[r * 65 + k] = A2[i];
            }
            __syncthreads();
            const int r = t >> 2, cb = (t & 3) * 16;
            float av[16];
            #pragma unroll
            for (int c = 0; c < 16; ++c) av[c] = 0.f;
            for (int k = 0; k < 64; ++k) {
                const float a = A2lds[r * 65 + k];
                const float4 w0 = *(const float4*)&Bm[k * 64 + cb];
                const float4 w1 = *(const float4*)&Bm[k * 64 + cb + 4];
                const float4 w2 = *(const float4*)&Bm[k * 64 + cb + 8];
                const float4 w3 = *(const float4*)&Bm[k * 64 + cb + 12];
                av[0]=fmaf(a,w0.x,av[0]); av[1]=fmaf(a,w0.y,av[1]); av[2]=fmaf(a,w0.z,av[2]); av[3]=fmaf(a,w0.w,av[3]);
                av[4]=fmaf(a,w1.x,av[4]); av[5]=fmaf(a,w1.y,av[5]); av[6]=fmaf(a,w1.z,av[6]); av[7]=fmaf(a,w1.w,av[7]);
                av[8]=fmaf(a,w2.x,av[8]); av[9]=fmaf(a,w2.y,av[9]); av[10]=fmaf(a,w2.z,av[10]); av[11]=fmaf(a,w2.w,av[11]);
                av[12]=fmaf(a,w3.x,av[12]); av[13]=fmaf(a,w3.y,av[13]); av[14]=fmaf(a,w3.z,av[14]); av[15]=fmaf(a,w3.w,av[15]);
            }
            #pragma unroll
            for (int c = 0; c < 16; ++c) C[r * 64 + cb + c] = av[c];
            if (t < 64) {
                float s = 0.f;
                for (int k = 0; k < 64; ++k) s = fmaf(bb[k], Bm[k * 64 + t], s);
                b21[(blk - 1) * 64 + t] = s;
            }
            __syncthreads();
        }
        unsigned short* hi = wsb + blk * 8192;
        unsigned short* lo = hi + 4096;
        for (int f = t; f < 512; f += 256) {
            const int s = f >> 8, n = (f >> 6) & 3, ll = f & 63;
            const int g = ll >> 4, col = n * 16 + (ll & 15);
            unsigned int uh[4], ul[4];
            #pragma unroll
            for (int j2 = 0; j2 < 4; ++j2) {
                const float a  = C[(s * 32 + g * 8 + j2 * 2)     * 64 + col];
                const float bq = C[(s * 32 + g * 8 + j2 * 2 + 1) * 64 + col];
                uh[j2] = pk2(a, bq);
                ul[j2] = pk2lo(a, bq, uh[j2]);
            }
            *(u32x4*)(hi + f * 8) = (u32x4){uh[0], uh[1], uh[2], uh[3]};
            *(u32x4*)(lo + f * 8) = (u32x4){ul[0], ul[1], ul[2], ul[3]};
        }
    } else if (blk < 15) {
        const int chunk = blk - 3;
        float* wc1c = sh;
        float* A2T  = sh + 6144;
        for (int i = t; i < 1536; i += 256) {
            const int row = i >> 3, q = i & 7;
            *(float4*)&wc1c[row * 32 + q * 4] = ldg4(wc1 + (size_t)row * C2DIM + chunk * 32 + q * 4);
        }
        for (int i = t; i < 8192; i += 256) {
            const int r = i >> 6, k = i & 63;
            const float v = (r < 64) ? win2[r * 64 + k] : wh2[(r - 64) * 64 + k];
            A2T[k * 129 + r] = v;
        }
        __syncthreads();
        float acc[32];
        if (t < 192) {
            const int R  = (t < 64) ? t : 64 + (t & 63);
            const int kb = (t >> 6) * 64;
            #pragma unroll
            for (int c = 0; c < 32; ++c) acc[c] = 0.f;
            for (int k = 0; k < 64; ++k) {
                const float a = A2T[k * 129 + R];
                const float* wr = &wc1c[(kb + k) * 32];
                #pragma unroll
                for (int c4 = 0; c4 < 8; ++c4) {
                    const float4 w = *(const float4*)&wr[c4 * 4];
                    acc[c4 * 4 + 0] = fmaf(a, w.x, acc[c4 * 4 + 0]);
                    acc[c4 * 4 + 1] = fmaf(a, w.y, acc[c4 * 4 + 1]);
                    acc[c4 * 4 + 2] = fmaf(a, w.z, acc[c4 * 4 + 2]);
                    acc[c4 * 4 + 3] = fmaf(a, w.w, acc[c4 * 4 + 3]);
                }
            }
        }
        __syncthreads();
        float* C2 = sh;
        if (t < 192) {
            #pragma unroll
            for (int c = 0; c < 32; ++c) C2[t * 33 + c] = acc[c];
        }
        __syncthreads();
        unsigned short* hi = wcf;
        unsigned short* lo = wcf + 73728;
        for (int i = t; i < 768; i += 256) {
            const int s = i / 128, rem = i % 128;
            const int nl = rem >> 6, ll = rem & 63;
            const int n = chunk * 2 + nl;
            const int e = (s * 24 + n) * 64 + ll;
            const int cl = nl * 16 + (ll & 15);
            const int k0 = s * 32 + (ll >> 4) * 8;
            unsigned int uh[4], ul[4];
            #pragma unroll
            for (int j2 = 0; j2 < 4; ++j2) {
                const float a  = C2[(k0 + j2 * 2)     * 33 + cl];
                const float bq = C2[(k0 + j2 * 2 + 1) * 33 + cl];
                uh[j2] = pk2(a, bq);
                ul[j2] = pk2lo(a, bq, uh[j2]);
            }
            *(u32x4*)(hi + e * 8) = (u32x4){uh[0], uh[1], uh[2], uh[3]};
            *(u32x4*)(lo + e * 8) = (u32x4){ul[0], ul[1], ul[2], ul[3]};
        }
    } else {
        for (int j = t; j < C2DIM; j += 256) {
            float s = 0.f;
            for (int k = 0; k < 64; ++k) {
                s = fmaf(bin2[k], wc1[(size_t)k * C2DIM + j], s);
                s = fmaf(bh2[k],  wc1[(size_t)(64 + k) * C2DIM + j], s);
                s = fmaf(bh2[k],  wc1[(size_t)(128 + k) * C2DIM + j], s);
            }
            bce[j] = bc1[j] + 32.0f * s;
        }
    }
}

// ==== main kernel: one BLOCK (2 waves) = one graph; wave w owns m-tile w ====
// launch_bounds(128, 6): 85-VGPR cap fits the ~70-reg live state (8-wave cap of
// 64 spilled ~45 MB scratch traffic in round 11); 24 waves/CU.
extern "C" __global__ void __launch_bounds__(128, 6)
gin_fused_kernel(const int* __restrict__ x, const int* __restrict__ los,
                 const int* __restrict__ eidx,
                 const float* __restrict__ emb,
                 const float* __restrict__ bin1,
                 const float* __restrict__ gin_g, const float* __restrict__ gin_b,
                 const float* __restrict__ bh1,
                 const float* __restrict__ gh_g, const float* __restrict__ gh_b,
                 const float* __restrict__ epsv,
                 const unsigned short* __restrict__ wsb,
                 const float* __restrict__ b21,
                 float* __restrict__ pooled_ws)
{
    __shared__ __align__(16) float scr[NNODE * HSTR];   // 8704 B shared state
    __shared__ float pcs[2][64];                        // colsum partials

    const int t  = threadIdx.x;
    const int w  = t >> 6;          // wave id = m-tile
    const int l  = t & 63;
    const int b  = blockIdx.x;
    const int lc = l & 15;
    const int lg = l >> 4;

    // ---- histogram (block-shared; cnt aliases scr) ----
    int* cnt = (int*)scr;
    #pragma unroll
    for (int i = 0; i < 8; ++i) cnt[t + 128 * i] = 0;
    __syncthreads();
    {
        const int ebase = b * EPG;
        const int goff  = b * NNODE;
        #pragma unroll
        for (int i = 0; i < 4; ++i) {
            const int e = ebase + t + 128 * i;
            const int sN = eidx[e] - goff;
            const int dN = eidx[NBATCH * EPG + e] - goff;
            atomicAdd(&cnt[dN * NNODE + sN], 1);
        }
    }
    __syncthreads();
    // ---- adjacency A-frag for this wave's m-tile (counts exact in bf16) ----
    u32x4 adjf;
    {
        const int rowA = w * 16 + lc;
        const int4 a0 = *(const int4*)&cnt[rowA * NNODE + lg * 8];
        const int4 a1 = *(const int4*)&cnt[rowA * NNODE + lg * 8 + 4];
        adjf = (u32x4){ pk2((float)a0.x, (float)a0.y), pk2((float)a0.z, (float)a0.w),
                        pk2((float)a1.x, (float)a1.y), pk2((float)a1.z, (float)a1.w) };
    }
    __syncthreads();   // cnt reads done before emb overwrite (cross-wave WAR)
    // ---- embedding -> scr: thread t loads node t>>2 (wave w -> own rows) ----
    {
        const int node = t >> 2;
        const int q = (t & 3) * 16;
        const int idx = (node < NNODE - 1) ? x[b * (NNODE - 1) + node] : los[b];
        const float* er = emb + ((size_t)(node * NVOCAB + idx)) * DIM + q;
        float* sr = scr + node * HSTR + q;
        #pragma unroll
        for (int i = 0; i < 4; ++i)
            *reinterpret_cast<float4*>(sr + i * 4) = ldg4(er + i * 4);
    }
    // (no barrier: wave w wrote exactly its own rows; st0 A-frag reads own rows)

    f32x4 acc[4];                    // this wave's 16x64 C-slice
    u32x4 azh[2], azl[2];

    for (int st = 0; st < 3; ++st) {
        const unsigned short* Wf = wsb + st * 8192;
        const float* bpost = st ? bh1  : bin1;
        const float* Gg    = st ? gh_g : gin_g;
        const float* Gb    = st ? gh_b : gin_b;
        const float sc = 1.0f + epsv[st];

        // stage input -> scr (own rows; stage0: embeddings already there)
        if (st) {
            #pragma unroll
            for (int n = 0; n < 4; ++n)
                #pragma unroll
                for (int r = 0; r < 4; ++r)
                    scr[(w * 16 + lg * 4 + r) * HSTR + n * 16 + lc] = acc[n][r];
        }
        // A-frags of input (own rows; in-wave lgkmcnt ordering)
        #pragma unroll
        for (int s = 0; s < 2; ++s) {
            const float4 v0 = *(const float4*)&scr[(w * 16 + lc) * HSTR + s * 32 + lg * 8];
            const float4 v1 = *(const float4*)&scr[(w * 16 + lc) * HSTR + s * 32 + lg * 8 + 4];
            azh[s] = (u32x4){ pk2(v0.x,v0.y), pk2(v0.z,v0.w), pk2(v1.x,v1.y), pk2(v1.z,v1.w) };
            azl[s] = (u32x4){ pk2lo(v0.x,v0.y,azh[s][0]), pk2lo(v0.z,v0.w,azh[s][1]),
                              pk2lo(v1.x,v1.y,azh[s][2]), pk2lo(v1.z,v1.w,azh[s][3]) };
        }
        // v = input @ W + b_pre
        #pragma unroll
        for (int n = 0; n < 4; ++n) {
            const float bp = st ? b21[(st - 1) * 64 + n * 16 + lc] : 0.f;
            acc[n] = (f32x4){bp, bp, bp, bp};
        }
        #pragma unroll
        for (int n = 0; n < 4; ++n)
            #pragma unroll
            for (int s = 0; s < 2; ++s) {
                const u32x4 wh = *(const u32x4*)(Wf +        ((s * 4 + n) * 64 + l) * 8);
                const u32x4 wl = *(const u32x4*)(Wf + 4096 + ((s * 4 + n) * 64 + l) * 8);
                acc[n] = MFMA(azh[s], wh, acc[n]);
                acc[n] = MFMA(azh[s], wl, acc[n]);
                acc[n] = MFMA(azl[s], wh, acc[n]);
            }
        // v -> scr (own rows)
        #pragma unroll
        for (int n = 0; n < 4; ++n)
            #pragma unroll
            for (int r = 0; r < 4; ++r)
                scr[(w * 16 + lg * 4 + r) * HSTR + n * 16 + lc] = acc[n][r];
        // in-place seeds: acc = sc*v + b_post
        #pragma unroll
        for (int n = 0; n < 4; ++n) {
            const float bq = bpost[n * 16 + lc];
            #pragma unroll
            for (int r = 0; r < 4; ++r)
                acc[n][r] = sc * acc[n][r] + bq;
        }
        __syncthreads();   // all 32 v-rows visible for agg B-frags
        // agg: acc += A_adj(m=w) @ v  (B-frags span all 32 src nodes)
        #pragma unroll
        for (int n = 0; n < 4; ++n) {
            float h[8];
            #pragma unroll
            for (int j = 0; j < 8; ++j) h[j] = scr[(lg * 8 + j) * HSTR + n * 16 + lc];
            const u32x4 hh = (u32x4){ pk2(h[0],h[1]), pk2(h[2],h[3]), pk2(h[4],h[5]), pk2(h[6],h[7]) };
            const u32x4 hl = (u32x4){ pk2lo(h[0],h[1],hh[0]), pk2lo(h[2],h[3],hh[1]),
                                      pk2lo(h[4],h[5],hh[2]), pk2lo(h[6],h[7],hh[3]) };
            acc[n] = MFMA(adjf, hh, acc[n]);
            acc[n] = MFMA(adjf, hl, acc[n]);
        }
        // LayerNorm + relu (in-register; this wave's 16 rows)
        {
            float gg[4], gb[4];
            #pragma unroll
            for (int n = 0; n < 4; ++n) { gg[n] = Gg[n * 16 + lc]; gb[n] = Gb[n * 16 + lc]; }
            #pragma unroll
            for (int r = 0; r < 4; ++r) {
                float a0 = acc[0][r], a1 = acc[1][r];
                float a2 = acc[2][r], a3 = acc[3][r];
                float s1 = a0 + a1 + a2 + a3;
                float s2 = a0 * a0 + a1 * a1 + a2 * a2 + a3 * a3;
                s1 += __shfl_xor(s1, 1); s1 += __shfl_xor(s1, 2);
                s1 += __shfl_xor(s1, 4); s1 += __shfl_xor(s1, 8);
                s2 += __shfl_xor(s2, 1); s2 += __shfl_xor(s2, 2);
                s2 += __shfl_xor(s2, 4); s2 += __shfl_xor(s2, 8);
                const float mu  = s1 * (1.0f / 64.0f);
                const float var = s2 * (1.0f / 64.0f) - mu * mu;
                const float inv = rsqrtf(var + LN_EPS);
                acc[0][r] = fmaxf((a0 - mu) * inv * gg[0] + gb[0], 0.f);
                acc[1][r] = fmaxf((a1 - mu) * inv * gg[1] + gb[1], 0.f);
                acc[2][r] = fmaxf((a2 - mu) * inv * gg[2] + gb[2], 0.f);
                acc[3][r] = fmaxf((a3 - mu) * inv * gg[3] + gb[3], 0.f);
            }
        }
        // colsum partial (this wave's 16 rows) -> pcs; merge across waves
        #pragma unroll
        for (int n = 0; n < 4; ++n) {
            float p = acc[n][0] + acc[n][1] + acc[n][2] + acc[n][3];
            p += __shfl_xor(p, 16);
            p += __shfl_xor(p, 32);
            if (l < 16) pcs[w][n * 16 + l] = p;
        }
        __syncthreads();
        if (t < 64)
            pooled_ws[(size_t)b * CDIM + st * DIM + t] = pcs[0][t] + pcs[1][t];
    }
}

// ---- classifier: out = relu(cs @ Wc_eff + bc_eff) @ wc2 + bc2 (unchanged) ----
extern "C" __global__ void __launch_bounds__(256)
classifier_kernel(const float* __restrict__ pooled_ws,
                  const unsigned short* __restrict__ wcf,
                  const float* __restrict__ bce, const float* __restrict__ wc2,
                  const float* __restrict__ bc2, float* __restrict__ out)
{
    #define PSTR 196
    __shared__ __align__(16) float P[16 * PSTR];
    __shared__ __align__(16) unsigned int afh[6 * 64 * 4];
    __shared__ __align__(16) unsigned int afl[6 * 64 * 4];
    __shared__ float rsum[4][16];

    const int b = blockIdx.x;
    const int t = threadIdx.x;
    const int l = t & 63;
    const int w = t >> 6;
    const unsigned short* wclo = wcf + 73728;

    for (int i = t; i < 16 * 48; i += 256) {
        const int row = i / 48, q = i % 48;
        const float4 v = ldg4(pooled_ws + ((size_t)(b * 16 + row)) * CDIM + q * 4);
        *reinterpret_cast<float4*>(&P[row * PSTR + q * 4]) = v;
    }
    __syncthreads();

    for (int e = t; e < 6 * 64; e += 256) {
        const int s = e >> 6, ll = e & 63;
        const int row = ll & 15;
        const int k0 = s * 32 + (ll >> 4) * 8;
        const float4 v0 = *reinterpret_cast<const float4*>(&P[row * PSTR + k0]);
        const float4 v1 = *reinterpret_cast<const float4*>(&P[row * PSTR + k0 + 4]);
        const float y[8] = { v0.x, v0.y, v0.z, v0.w, v1.x, v1.y, v1.z, v1.w };
        unsigned int uh[4], ul[4];
        #pragma unroll
        for (int j2 = 0; j2 < 4; ++j2) {
            uh[j2] = pk2(y[j2 * 2], y[j2 * 2 + 1]);
            ul[j2] = pk2lo(y[j2 * 2], y[j2 * 2 + 1], uh[j2]);
        }
        *reinterpret_cast<u32x4*>(&afh[e * 4]) = (u32x4){uh[0], uh[1], uh[2], uh[3]};
        *reinterpret_cast<u32x4*>(&afl[e * 4]) = (u32x4){ul[0], ul[1], ul[2], ul[3]};
    }
    __syncthreads();

    float part[4] = {0.f, 0.f, 0.f, 0.f};
    for (int nt = 0; nt < 6; ++nt) {
        const int n = w * 6 + nt;
        f32x4 acc = {0.f, 0.f, 0.f, 0.f};
        #pragma unroll
        for (int s = 0; s < 6; ++s) {
            const u32x4 ah = *(const u32x4*)&afh[(s * 64 + l) * 4];
            const u32x4 al = *(const u32x4*)&afl[(s * 64 + l) * 4];
            const u32x4 bh = *(const u32x4*)&wcf [((s * 24 + n) * 64 + l) * 8];
            const u32x4 bl = *(const u32x4*)&wclo[((s * 24 + n) * 64 + l) * 8];
            acc = MFMA(ah, bh, acc);
            acc = MFMA(ah, bl, acc);
            acc = MFMA(al, bh, acc);
        }
        const int col = n * 16 + (l & 15);
        const float bias = bce[col], w2 = wc2[col];
        #pragma unroll
        for (int r = 0; r < 4; ++r)
            part[r] += fmaxf(acc[r] + bias, 0.f) * w2;
    }
    #pragma unroll
    for (int r = 0; r < 4; ++r) {
        part[r] += __shfl_xor(part[r], 1);
        part[r] += __shfl_xor(part[r], 2);
        part[r] += __shfl_xor(part[r], 4);
        part[r] += __shfl_xor(part[r], 8);
    }
    if ((l & 15) == 0) {
        const int g = l >> 4;
        #pragma unroll
        for (int r = 0; r < 4; ++r) rsum[w][g * 4 + r] = part[r];
    }
    __syncthreads();
    if (t < 16)
        out[b * 16 + t] = rsum[0][t] + rsum[1][t] + rsum[2][t] + rsum[3][t] + bc2[0];
}

extern "C" void kernel_launch(void* const* d_in, const int* in_sizes, int n_in,
                              void* d_out, int out_size, void* d_ws, size_t ws_size,
                              hipStream_t stream)
{
    const int*   x     = (const int*)d_in[0];
    const int*   los   = (const int*)d_in[1];
    const int*   eidx  = (const int*)d_in[2];
    const float* emb   = (const float*)d_in[3];
    const float* win1  = (const float*)d_in[4];
    const float* bin1  = (const float*)d_in[5];
    const float* gin_g = (const float*)d_in[6];
    const float* gin_b = (const float*)d_in[7];
    const float* win2  = (const float*)d_in[8];
    const float* bin2  = (const float*)d_in[9];
    const float* wh1   = (const float*)d_in[10];
    const float* bh1   = (const float*)d_in[11];
    const float* gh_g  = (const float*)d_in[12];
    const float* gh_b  = (const float*)d_in[13];
    const float* wh2   = (const float*)d_in[14];
    const float* bh2   = (const float*)d_in[15];
    const float* epsv  = (const float*)d_in[16];
    const float* wc1   = (const float*)d_in[17];
    const float* bc1   = (const float*)d_in[18];
    const float* wc2   = (const float*)d_in[19];
    const float* bc2   = (const float*)d_in[20];
    float* out = (float*)d_out;

    unsigned short* wsb = (unsigned short*)((char*)d_ws + WS_WFRAG_OFF);
    float*          b21 = (float*)((char*)d_ws + WS_B21_OFF);
    unsigned short* wcf = (unsigned short*)((char*)d_ws + WS_WCF_OFF);
    float*          bce = (float*)((char*)d_ws + WS_BCE_OFF);
    float*          cs  = (float*)((char*)d_ws + WS_POOL_OFF);

    hipLaunchKernelGGL(prep_w_kernel, dim3(16), dim3(256), 0, stream,
                       win1, win2, wh1, wh2, wc1, bin2, bh2, bc1,
                       wsb, wcf, b21, bce);
    hipLaunchKernelGGL(gin_fused_kernel, dim3(NBATCH), dim3(128), 0, stream,
                       x, los, eidx, emb, bin1, gin_g, gin_b,
                       bh1, gh_g, gh_b, epsv,
                       (const unsigned short*)wsb, (const float*)b21, cs);
    hipLaunchKernelGGL(classifier_kernel, dim3(NBATCH / 16), dim3(256), 0, stream,
                       (const float*)cs, (const unsigned short*)wcf,
                       (const float*)bce, wc2, bc2, out);
}

// Round 13
// 62.713 us; speedup vs baseline: 1.0969x; 1.0476x over previous
//
#include <hip/hip_runtime.h>

#define NBATCH 4096
#define NNODE  32
#define NVOCAB 100
#define DIM    64
#define EPG    512
#define HSTR   68      // padded fp32 LDS row stride
#define LN_EPS 1e-5f
#define CDIM   192
#define C2DIM  384
#define GWORDS 2304    // per-graph LDS words: max(32*68 fp32, 2*64*18 pair-words)

// workspace layout (bytes)
#define WS_WFRAG_OFF   0         // 3 x 16384 B stage-W frags (Win1, Win2@Wh1, Wh2@Wh1)
#define WS_B21_OFF     49152     // 128 floats: b21a(64), b21b(64)
#define WS_WCF_OFF     65536     // Wc_eff frags: hi 147456 + lo 147456
#define WS_BCE_OFF     360448    // bc_eff: 384 floats
#define WS_POOL_OFF    364544    // cs 4096*192 f32

typedef float          f32x4  __attribute__((ext_vector_type(4)));
typedef unsigned int   u32x4  __attribute__((ext_vector_type(4)));
typedef __bf16         bf16x8 __attribute__((ext_vector_type(8)));

__device__ __forceinline__ float4 ldg4(const float* __restrict__ p) {
    return *reinterpret_cast<const float4*>(p);
}
__device__ __forceinline__ unsigned short f2bf(float f) {
    return __builtin_bit_cast(unsigned short, static_cast<__bf16>(f));
}
__device__ __forceinline__ float bf2f(unsigned short h) {
    return static_cast<float>(__builtin_bit_cast(__bf16, h));
}
__device__ __forceinline__ unsigned int pk2(float a, float b) {
    return (unsigned int)f2bf(a) | ((unsigned int)f2bf(b) << 16);
}
__device__ __forceinline__ unsigned int pk2lo(float a, float b, unsigned int hi) {
    const float ra = a - bf2f((unsigned short)(hi & 0xffff));
    const float rb = b - bf2f((unsigned short)(hi >> 16));
    return pk2(ra, rb);
}
__device__ __forceinline__ bf16x8 as_bf(u32x4 v) {
    return __builtin_bit_cast(bf16x8, v);
}
#define MFMA(a, b, c) __builtin_amdgcn_mfma_f32_16x16x32_bf16(as_bf(a), as_bf(b), (c), 0, 0, 0)

// ---- pre-kernel (unchanged) ----
extern "C" __global__ void __launch_bounds__(256)
prep_w_kernel(const float* __restrict__ win1, const float* __restrict__ win2,
              const float* __restrict__ wh1,  const float* __restrict__ wh2,
              const float* __restrict__ wc1,  const float* __restrict__ bin2,
              const float* __restrict__ bh2,  const float* __restrict__ bc1,
              unsigned short* __restrict__ wsb, unsigned short* __restrict__ wcf,
              float* __restrict__ b21, float* __restrict__ bce)
{
    __shared__ float sh[14400];
    const int blk = blockIdx.x, t = threadIdx.x;

    if (blk < 3) {
        float* C = sh + 4096;
        if (blk == 0) {
            for (int i = t; i < 1024; i += 256)
                *(float4*)&C[i * 4] = ldg4(win1 + i * 4);
            __syncthreads();
        } else {
            const float* A2 = (blk == 1) ? win2 : wh2;
            const float* bb = (blk == 1) ? bin2 : bh2;
            float* Bm    = sh;
            float* A2lds = sh + 8192;
            for (int i = t; i < 1024; i += 256)
                *(float4*)&Bm[i * 4] = ldg4(wh1 + i * 4);
            for (int i = t; i < 4096; i += 256) {
                const int r = i >> 6, k = i & 63;
                A2lds[r * 65 + k] = A2[i];
            }
            __syncthreads();
            const int r = t >> 2, cb = (t & 3) * 16;
            float av[16];
            #pragma unroll
            for (int c = 0; c < 16; ++c) av[c] = 0.f;
            for (int k = 0; k < 64; ++k) {
                const float a = A2lds[r * 65 + k];
                const float4 w0 = *(const float4*)&Bm[k * 64 + cb];
                const float4 w1 = *(const float4*)&Bm[k * 64 + cb + 4];
                const float4 w2 = *(const float4*)&Bm[k * 64 + cb + 8];
                const float4 w3 = *(const float4*)&Bm[k * 64 + cb + 12];
                av[0]=fmaf(a,w0.x,av[0]); av[1]=fmaf(a,w0.y,av[1]); av[2]=fmaf(a,w0.z,av[2]); av[3]=fmaf(a,w0.w,av[3]);
                av[4]=fmaf(a,w1.x,av[4]); av[5]=fmaf(a,w1.y,av[5]); av[6]=fmaf(a,w1.z,av[6]); av[7]=fmaf(a,w1.w,av[7]);
                av[8]=fmaf(a,w2.x,av[8]); av[9]=fmaf(a,w2.y,av[9]); av[10]=fmaf(a,w2.z,av[10]); av[11]=fmaf(a,w2.w,av[11]);
                av[12]=fmaf(a,w3.x,av[12]); av[13]=fmaf(a,w3.y,av[13]); av[14]=fmaf(a,w3.z,av[14]); av[15]=fmaf(a,w3.w,av[15]);
            }
            #pragma unroll
            for (int c = 0; c < 16; ++c) C[r * 64 + cb + c] = av[c];
            if (t < 64) {
                float s = 0.f;
                for (int k = 0; k < 64; ++k) s = fmaf(bb[k], Bm[k * 64 + t], s);
                b21[(blk - 1) * 64 + t] = s;
            }
            __syncthreads();
        }
        unsigned short* hi = wsb + blk * 8192;
        unsigned short* lo = hi + 4096;
        for (int f = t; f < 512; f += 256) {
            const int s = f >> 8, n = (f >> 6) & 3, ll = f & 63;
            const int g = ll >> 4, col = n * 16 + (ll & 15);
            unsigned int uh[4], ul[4];
            #pragma unroll
            for (int j2 = 0; j2 < 4; ++j2) {
                const float a  = C[(s * 32 + g * 8 + j2 * 2)     * 64 + col];
                const float bq = C[(s * 32 + g * 8 + j2 * 2 + 1) * 64 + col];
                uh[j2] = pk2(a, bq);
                ul[j2] = pk2lo(a, bq, uh[j2]);
            }
            *(u32x4*)(hi + f * 8) = (u32x4){uh[0], uh[1], uh[2], uh[3]};
            *(u32x4*)(lo + f * 8) = (u32x4){ul[0], ul[1], ul[2], ul[3]};
        }
    } else if (blk < 15) {
        const int chunk = blk - 3;
        float* wc1c = sh;
        float* A2T  = sh + 6144;
        for (int i = t; i < 1536; i += 256) {
            const int row = i >> 3, q = i & 7;
            *(float4*)&wc1c[row * 32 + q * 4] = ldg4(wc1 + (size_t)row * C2DIM + chunk * 32 + q * 4);
        }
        for (int i = t; i < 8192; i += 256) {
            const int r = i >> 6, k = i & 63;
            const float v = (r < 64) ? win2[r * 64 + k] : wh2[(r - 64) * 64 + k];
            A2T[k * 129 + r] = v;
        }
        __syncthreads();
        float acc[32];
        if (t < 192) {
            const int R  = (t < 64) ? t : 64 + (t & 63);
            const int kb = (t >> 6) * 64;
            #pragma unroll
            for (int c = 0; c < 32; ++c) acc[c] = 0.f;
            for (int k = 0; k < 64; ++k) {
                const float a = A2T[k * 129 + R];
                const float* wr = &wc1c[(kb + k) * 32];
                #pragma unroll
                for (int c4 = 0; c4 < 8; ++c4) {
                    const float4 w = *(const float4*)&wr[c4 * 4];
                    acc[c4 * 4 + 0] = fmaf(a, w.x, acc[c4 * 4 + 0]);
                    acc[c4 * 4 + 1] = fmaf(a, w.y, acc[c4 * 4 + 1]);
                    acc[c4 * 4 + 2] = fmaf(a, w.z, acc[c4 * 4 + 2]);
                    acc[c4 * 4 + 3] = fmaf(a, w.w, acc[c4 * 4 + 3]);
                }
            }
        }
        __syncthreads();
        float* C2 = sh;
        if (t < 192) {
            #pragma unroll
            for (int c = 0; c < 32; ++c) C2[t * 33 + c] = acc[c];
        }
        __syncthreads();
        unsigned short* hi = wcf;
        unsigned short* lo = wcf + 73728;
        for (int i = t; i < 768; i += 256) {
            const int s = i / 128, rem = i % 128;
            const int nl = rem >> 6, ll = rem & 63;
            const int n = chunk * 2 + nl;
            const int e = (s * 24 + n) * 64 + ll;
            const int cl = nl * 16 + (ll & 15);
            const int k0 = s * 32 + (ll >> 4) * 8;
            unsigned int uh[4], ul[4];
            #pragma unroll
            for (int j2 = 0; j2 < 4; ++j2) {
                const float a  = C2[(k0 + j2 * 2)     * 33 + cl];
                const float bq = C2[(k0 + j2 * 2 + 1) * 33 + cl];
                uh[j2] = pk2(a, bq);
                ul[j2] = pk2lo(a, bq, uh[j2]);
            }
            *(u32x4*)(hi + e * 8) = (u32x4){uh[0], uh[1], uh[2], uh[3]};
            *(u32x4*)(lo + e * 8) = (u32x4){ul[0], ul[1], ul[2], ul[3]};
        }
    } else {
        for (int j = t; j < C2DIM; j += 256) {
            float s = 0.f;
            for (int k = 0; k < 64; ++k) {
                s = fmaf(bin2[k], wc1[(size_t)k * C2DIM + j], s);
                s = fmaf(bh2[k],  wc1[(size_t)(64 + k) * C2DIM + j], s);
                s = fmaf(bh2[k],  wc1[(size_t)(128 + k) * C2DIM + j], s);
            }
            bce[j] = bc1[j] + 32.0f * s;
        }
    }
}

// ==== main kernel: one WAVE = one graph; zero barriers; register-direct agg pairs ====
extern "C" __global__ void __launch_bounds__(256, 4)
gin_fused_kernel(const int* __restrict__ x, const int* __restrict__ los,
                 const int* __restrict__ eidx,
                 const float* __restrict__ emb,
                 const float* __restrict__ bin1,
                 const float* __restrict__ gin_g, const float* __restrict__ gin_b,
                 const float* __restrict__ bh1,
                 const float* __restrict__ gh_g, const float* __restrict__ gh_b,
                 const float* __restrict__ epsv,
                 const unsigned short* __restrict__ wsb,
                 const float* __restrict__ b21,
                 float* __restrict__ pooled_ws)
{
    __shared__ __align__(16) float S[4 * GWORDS];   // per-wave private region (9216 B)

    const int t  = threadIdx.x;
    const int wv = t >> 6;
    const int l  = t & 63;
    const int b  = blockIdx.x * 4 + wv;
    float* scr = &S[wv * GWORDS];                   // fp32 H [32][68] (aliased by pair buf)
    unsigned int* bp = (unsigned int*)scr;          // pair buf: hi [64 col][18], lo at +1152
    const int lc = l & 15;
    const int lg = l >> 4;

    // ---- histogram (wave-local; cnt aliases scr) ----
    int* cnt = (int*)scr;
    #pragma unroll
    for (int i = 0; i < 16; ++i) cnt[l + 64 * i] = 0;
    {
        const int ebase = b * EPG;
        const int goff  = b * NNODE;
        #pragma unroll
        for (int i = 0; i < 8; ++i) {
            const int e = ebase + l + 64 * i;
            const int sN = eidx[e] - goff;
            const int dN = eidx[NBATCH * EPG + e] - goff;
            atomicAdd(&cnt[dN * NNODE + sN], 1);
        }
    }
    // ---- adjacency A-frags (hi only; counts exact in bf16) ----
    u32x4 adjf[2];
    #pragma unroll
    for (int m = 0; m < 2; ++m) {
        const int4 a0 = *(const int4*)&cnt[(m * 16 + lc) * NNODE + lg * 8];
        const int4 a1 = *(const int4*)&cnt[(m * 16 + lc) * NNODE + lg * 8 + 4];
        adjf[m] = (u32x4){ pk2((float)a0.x, (float)a0.y), pk2((float)a0.z, (float)a0.w),
                           pk2((float)a1.x, (float)a1.y), pk2((float)a1.z, (float)a1.w) };
    }
    // ---- embedding -> scr (in-order LDS pipe: WAR vs cnt reads safe) ----
    {
        const int node = l >> 1;
        const int idx = (node < NNODE - 1) ? x[b * (NNODE - 1) + node] : los[b];
        const float* er = emb + ((size_t)(node * NVOCAB + idx)) * DIM + (l & 1) * 32;
        float* sr = scr + node * HSTR + (l & 1) * 32;
        #pragma unroll
        for (int i = 0; i < 8; ++i)
            *reinterpret_cast<float4*>(sr + i * 4) = ldg4(er + i * 4);
    }

    f32x4 acc[2][4];
    u32x4 azh[2][2], azl[2][2];

    for (int st = 0; st < 3; ++st) {
        const unsigned short* Wf = wsb + st * 8192;
        const float* bpost = st ? bh1  : bin1;
        const float* Gg    = st ? gh_g : gin_g;
        const float* Gb    = st ? gh_b : gin_b;
        const float sc = 1.0f + epsv[st];

        // stage input -> scr fp32 (stage0: embeddings already there)
        if (st) {
            #pragma unroll
            for (int m = 0; m < 2; ++m)
                #pragma unroll
                for (int n = 0; n < 4; ++n)
                    #pragma unroll
                    for (int r = 0; r < 4; ++r)
                        scr[(m * 16 + lg * 4 + r) * HSTR + n * 16 + lc] = acc[m][n][r];
        }
        // A-frags of input (genuine transpose through LDS)
        #pragma unroll
        for (int m = 0; m < 2; ++m)
            #pragma unroll
            for (int s = 0; s < 2; ++s) {
                const float4 v0 = *(const float4*)&scr[(m * 16 + lc) * HSTR + s * 32 + lg * 8];
                const float4 v1 = *(const float4*)&scr[(m * 16 + lc) * HSTR + s * 32 + lg * 8 + 4];
                azh[m][s] = (u32x4){ pk2(v0.x,v0.y), pk2(v0.z,v0.w), pk2(v1.x,v1.y), pk2(v1.z,v1.w) };
                azl[m][s] = (u32x4){ pk2lo(v0.x,v0.y,azh[m][s][0]), pk2lo(v0.z,v0.w,azh[m][s][1]),
                                     pk2lo(v1.x,v1.y,azh[m][s][2]), pk2lo(v1.z,v1.w,azh[m][s][3]) };
            }
        // v = input @ W + b_pre
        #pragma unroll
        for (int n = 0; n < 4; ++n) {
            const float bpv = st ? b21[(st - 1) * 64 + n * 16 + lc] : 0.f;
            #pragma unroll
            for (int m = 0; m < 2; ++m)
                acc[m][n] = (f32x4){bpv, bpv, bpv, bpv};
        }
        #pragma unroll
        for (int n = 0; n < 4; ++n)
            #pragma unroll
            for (int s = 0; s < 2; ++s) {
                const u32x4 wh = *(const u32x4*)(Wf +        ((s * 4 + n) * 64 + l) * 8);
                const u32x4 wl = *(const u32x4*)(Wf + 4096 + ((s * 4 + n) * 64 + l) * 8);
                #pragma unroll
                for (int m = 0; m < 2; ++m) {
                    acc[m][n] = MFMA(azh[m][s], wh, acc[m][n]);
                    acc[m][n] = MFMA(azh[m][s], wl, acc[m][n]);
                    acc[m][n] = MFMA(azl[m][s], wh, acc[m][n]);
                }
            }
        // v-pairs (bf16 hi/lo) -> pair buf DIRECTLY from registers.
        // acc[m][n][{0,1}] / {2,3} are node-pairs p0 = m*8+lg*2, p0+1 for col n*16+lc.
        // (fp32 H region is dead after the A-frag reads above; in-wave LDS order is safe)
        #pragma unroll
        for (int m = 0; m < 2; ++m)
            #pragma unroll
            for (int n = 0; n < 4; ++n) {
                const int col = n * 16 + lc;
                const int p0  = m * 8 + lg * 2;
                uint2 h2, l2;
                h2.x = pk2(acc[m][n][0], acc[m][n][1]);
                h2.y = pk2(acc[m][n][2], acc[m][n][3]);
                l2.x = pk2lo(acc[m][n][0], acc[m][n][1], h2.x);
                l2.y = pk2lo(acc[m][n][2], acc[m][n][3], h2.y);
                *(uint2*)&bp[col * 18 + p0]        = h2;
                *(uint2*)&bp[1152 + col * 18 + p0] = l2;
            }
        // in-place seeds: acc = sc*v + b_post
        #pragma unroll
        for (int n = 0; n < 4; ++n) {
            const float bq = bpost[n * 16 + lc];
            #pragma unroll
            for (int m = 0; m < 2; ++m)
                #pragma unroll
                for (int r = 0; r < 4; ++r)
                    acc[m][n][r] = sc * acc[m][n][r] + bq;
        }
        // agg: acc += A @ v — B-frags are raw b64 reads, zero conversion
        #pragma unroll
        for (int n = 0; n < 4; ++n) {
            const int base = (n * 16 + lc) * 18 + lg * 4;
            const uint2 ha = *(const uint2*)&bp[base];
            const uint2 hb = *(const uint2*)&bp[base + 2];
            const uint2 la = *(const uint2*)&bp[1152 + base];
            const uint2 lb = *(const uint2*)&bp[1152 + base + 2];
            const u32x4 hh = (u32x4){ha.x, ha.y, hb.x, hb.y};
            const u32x4 hl = (u32x4){la.x, la.y, lb.x, lb.y};
            #pragma unroll
            for (int m = 0; m < 2; ++m) {
                acc[m][n] = MFMA(adjf[m], hh, acc[m][n]);
                acc[m][n] = MFMA(adjf[m], hl, acc[m][n]);
            }
        }
        // LayerNorm + relu (in-register)
        {
            float gg[4], gb[4];
            #pragma unroll
            for (int n = 0; n < 4; ++n) { gg[n] = Gg[n * 16 + lc]; gb[n] = Gb[n * 16 + lc]; }
            #pragma unroll
            for (int m = 0; m < 2; ++m)
                #pragma unroll
                for (int r = 0; r < 4; ++r) {
                    float a0 = acc[m][0][r], a1 = acc[m][1][r];
                    float a2 = acc[m][2][r], a3 = acc[m][3][r];
                    float s1 = a0 + a1 + a2 + a3;
                    float s2 = a0 * a0 + a1 * a1 + a2 * a2 + a3 * a3;
                    s1 += __shfl_xor(s1, 1); s1 += __shfl_xor(s1, 2);
                    s1 += __shfl_xor(s1, 4); s1 += __shfl_xor(s1, 8);
                    s2 += __shfl_xor(s2, 1); s2 += __shfl_xor(s2, 2);
                    s2 += __shfl_xor(s2, 4); s2 += __shfl_xor(s2, 8);
                    const float mu  = s1 * (1.0f / 64.0f);
                    const float var = s2 * (1.0f / 64.0f) - mu * mu;
                    const float inv = rsqrtf(var + LN_EPS);
                    acc[m][0][r] = fmaxf((a0 - mu) * inv * gg[0] + gb[0], 0.f);
                    acc[m][1][r] = fmaxf((a1 - mu) * inv * gg[1] + gb[1], 0.f);
                    acc[m][2][r] = fmaxf((a2 - mu) * inv * gg[2] + gb[2], 0.f);
                    acc[m][3][r] = fmaxf((a3 - mu) * inv * gg[3] + gb[3], 0.f);
                }
        }
        // cs[st] = colsum(y) -> workspace
        #pragma unroll
        for (int n = 0; n < 4; ++n) {
            float p = 0.f;
            #pragma unroll
            for (int m = 0; m < 2; ++m)
                #pragma unroll
                for (int r = 0; r < 4; ++r) p += acc[m][n][r];
            p += __shfl_xor(p, 16);
            p += __shfl_xor(p, 32);
            if (l < 16)
                pooled_ws[(size_t)b * CDIM + st * DIM + n * 16 + l] = p;
        }
    }
}

// ---- classifier: out = relu(cs @ Wc_eff + bc_eff) @ wc2 + bc2 (unchanged) ----
extern "C" __global__ void __launch_bounds__(256)
classifier_kernel(const float* __restrict__ pooled_ws,
                  const unsigned short* __restrict__ wcf,
                  const float* __restrict__ bce, const float* __restrict__ wc2,
                  const float* __restrict__ bc2, float* __restrict__ out)
{
    #define PSTR 196
    __shared__ __align__(16) float P[16 * PSTR];
    __shared__ __align__(16) unsigned int afh[6 * 64 * 4];
    __shared__ __align__(16) unsigned int afl[6 * 64 * 4];
    __shared__ float rsum[4][16];

    const int b = blockIdx.x;
    const int t = threadIdx.x;
    const int l = t & 63;
    const int w = t >> 6;
    const unsigned short* wclo = wcf + 73728;

    for (int i = t; i < 16 * 48; i += 256) {
        const int row = i / 48, q = i % 48;
        const float4 v = ldg4(pooled_ws + ((size_t)(b * 16 + row)) * CDIM + q * 4);
        *reinterpret_cast<float4*>(&P[row * PSTR + q * 4]) = v;
    }
    __syncthreads();

    for (int e = t; e < 6 * 64; e += 256) {
        const int s = e >> 6, ll = e & 63;
        const int row = ll & 15;
        const int k0 = s * 32 + (ll >> 4) * 8;
        const float4 v0 = *reinterpret_cast<const float4*>(&P[row * PSTR + k0]);
        const float4 v1 = *reinterpret_cast<const float4*>(&P[row * PSTR + k0 + 4]);
        const float y[8] = { v0.x, v0.y, v0.z, v0.w, v1.x, v1.y, v1.z, v1.w };
        unsigned int uh[4], ul[4];
        #pragma unroll
        for (int j2 = 0; j2 < 4; ++j2) {
            uh[j2] = pk2(y[j2 * 2], y[j2 * 2 + 1]);
            ul[j2] = pk2lo(y[j2 * 2], y[j2 * 2 + 1], uh[j2]);
        }
        *reinterpret_cast<u32x4*>(&afh[e * 4]) = (u32x4){uh[0], uh[1], uh[2], uh[3]};
        *reinterpret_cast<u32x4*>(&afl[e * 4]) = (u32x4){ul[0], ul[1], ul[2], ul[3]};
    }
    __syncthreads();

    float part[4] = {0.f, 0.f, 0.f, 0.f};
    for (int nt = 0; nt < 6; ++nt) {
        const int n = w * 6 + nt;
        f32x4 acc = {0.f, 0.f, 0.f, 0.f};
        #pragma unroll
        for (int s = 0; s < 6; ++s) {
            const u32x4 ah = *(const u32x4*)&afh[(s * 64 + l) * 4];
            const u32x4 al = *(const u32x4*)&afl[(s * 64 + l) * 4];
            const u32x4 bh = *(const u32x4*)&wcf [((s * 24 + n) * 64 + l) * 8];
            const u32x4 bl = *(const u32x4*)&wclo[((s * 24 + n) * 64 + l) * 8];
            acc = MFMA(ah, bh, acc);
            acc = MFMA(ah, bl, acc);
            acc = MFMA(al, bh, acc);
        }
        const int col = n * 16 + (l & 15);
        const float bias = bce[col], w2 = wc2[col];
        #pragma unroll
        for (int r = 0; r < 4; ++r)
            part[r] += fmaxf(acc[r] + bias, 0.f) * w2;
    }
    #pragma unroll
    for (int r = 0; r < 4; ++r) {
        part[r] += __shfl_xor(part[r], 1);
        part[r] += __shfl_xor(part[r], 2);
        part[r] += __shfl_xor(part[r], 4);
        part[r] += __shfl_xor(part[r], 8);
    }
    if ((l & 15) == 0) {
        const int g = l >> 4;
        #pragma unroll
        for (int r = 0; r < 4; ++r) rsum[w][g * 4 + r] = part[r];
    }
    __syncthreads();
    if (t < 16)
        out[b * 16 + t] = rsum[0][t] + rsum[1][t] + rsum[2][t] + rsum[3][t] + bc2[0];
}

extern "C" void kernel_launch(void* const* d_in, const int* in_sizes, int n_in,
                              void* d_out, int out_size, void* d_ws, size_t ws_size,
                              hipStream_t stream)
{
    const int*   x     = (const int*)d_in[0];
    const int*   los   = (const int*)d_in[1];
    const int*   eidx  = (const int*)d_in[2];
    const float* emb   = (const float*)d_in[3];
    const float* win1  = (const float*)d_in[4];
    const float* bin1  = (const float*)d_in[5];
    const float* gin_g = (const float*)d_in[6];
    const float* gin_b = (const float*)d_in[7];
    const float* win2  = (const float*)d_in[8];
    const float* bin2  = (const float*)d_in[9];
    const float* wh1   = (const float*)d_in[10];
    const float* bh1   = (const float*)d_in[11];
    const float* gh_g  = (const float*)d_in[12];
    const float* gh_b  = (const float*)d_in[13];
    const float* wh2   = (const float*)d_in[14];
    const float* bh2   = (const float*)d_in[15];
    const float* epsv  = (const float*)d_in[16];
    const float* wc1   = (const float*)d_in[17];
    const float* bc1   = (const float*)d_in[18];
    const float* wc2   = (const float*)d_in[19];
    const float* bc2   = (const float*)d_in[20];
    float* out = (float*)d_out;

    unsigned short* wsb = (unsigned short*)((char*)d_ws + WS_WFRAG_OFF);
    float*          b21 = (float*)((char*)d_ws + WS_B21_OFF);
    unsigned short* wcf = (unsigned short*)((char*)d_ws + WS_WCF_OFF);
    float*          bce = (float*)((char*)d_ws + WS_BCE_OFF);
    float*          cs  = (float*)((char*)d_ws + WS_POOL_OFF);

    hipLaunchKernelGGL(prep_w_kernel, dim3(16), dim3(256), 0, stream,
                       win1, win2, wh1, wh2, wc1, bin2, bh2, bc1,
                       wsb, wcf, b21, bce);
    hipLaunchKernelGGL(gin_fused_kernel, dim3(NBATCH / 4), dim3(256), 0, stream,
                       x, los, eidx, emb, bin1, gin_g, gin_b,
                       bh1, gh_g, gh_b, epsv,
                       (const unsigned short*)wsb, (const float*)b21, cs);
    hipLaunchKernelGGL(classifier_kernel, dim3(NBATCH / 16), dim3(256), 0, stream,
                       (const float*)cs, (const unsigned short*)wcf,
                       (const float*)bce, wc2, bc2, out);
}

// Round 14
// 54.170 us; speedup vs baseline: 1.2699x; 1.1577x over previous
//
#include <hip/hip_runtime.h>

#define NBATCH 4096
#define NNODE  32
#define NVOCAB 100
#define DIM    64
#define EPG    512
#define HSTR   68      // padded fp32 LDS row stride
#define LN_EPS 1e-5f
#define CDIM   192
#define C2DIM  384
#define GWORDS 2304    // per-graph LDS words: max(32*68 fp32, 2*64*18 pair-words)

// workspace layout (bytes)
#define WS_WFRAG_OFF   0         // 3 x 16384 B stage-W frags (Win1, Win2@Wh1, Wh2@Wh1)
#define WS_B21_OFF     49152     // 128 floats: b21a(64), b21b(64)
#define WS_WCF_OFF     65536     // Wc_eff frags: hi 147456 + lo 147456
#define WS_BCE_OFF     360448    // bc_eff: 384 floats
#define WS_POOL_OFF    364544    // cs 4096*192 f32

typedef float          f32x4  __attribute__((ext_vector_type(4)));
typedef unsigned int   u32x4  __attribute__((ext_vector_type(4)));
typedef __bf16         bf16x8 __attribute__((ext_vector_type(8)));

__device__ __forceinline__ float4 ldg4(const float* __restrict__ p) {
    return *reinterpret_cast<const float4*>(p);
}
__device__ __forceinline__ unsigned short f2bf(float f) {
    return __builtin_bit_cast(unsigned short, static_cast<__bf16>(f));
}
__device__ __forceinline__ float bf2f(unsigned short h) {
    return static_cast<float>(__builtin_bit_cast(__bf16, h));
}
__device__ __forceinline__ unsigned int pk2(float a, float b) {
    return (unsigned int)f2bf(a) | ((unsigned int)f2bf(b) << 16);
}
__device__ __forceinline__ unsigned int pk2lo(float a, float b, unsigned int hi) {
    const float ra = a - bf2f((unsigned short)(hi & 0xffff));
    const float rb = b - bf2f((unsigned short)(hi >> 16));
    return pk2(ra, rb);
}
__device__ __forceinline__ bf16x8 as_bf(u32x4 v) {
    return __builtin_bit_cast(bf16x8, v);
}
// sum across the 16 lanes of a DPP row via rotation butterfly — pure VALU, no LDS pipe
__device__ __forceinline__ float rowsum16(float v) {
    int x = __builtin_bit_cast(int, v);
    v += __builtin_bit_cast(float, __builtin_amdgcn_update_dpp(0, x, 0x128, 0xF, 0xF, false)); // ror:8
    x = __builtin_bit_cast(int, v);
    v += __builtin_bit_cast(float, __builtin_amdgcn_update_dpp(0, x, 0x124, 0xF, 0xF, false)); // ror:4
    x = __builtin_bit_cast(int, v);
    v += __builtin_bit_cast(float, __builtin_amdgcn_update_dpp(0, x, 0x122, 0xF, 0xF, false)); // ror:2
    x = __builtin_bit_cast(int, v);
    v += __builtin_bit_cast(float, __builtin_amdgcn_update_dpp(0, x, 0x121, 0xF, 0xF, false)); // ror:1
    return v;
}
#define MFMA(a, b, c) __builtin_amdgcn_mfma_f32_16x16x32_bf16(as_bf(a), as_bf(b), (c), 0, 0, 0)

// ---- pre-kernel (unchanged) ----
extern "C" __global__ void __launch_bounds__(256)
prep_w_kernel(const float* __restrict__ win1, const float* __restrict__ win2,
              const float* __restrict__ wh1,  const float* __restrict__ wh2,
              const float* __restrict__ wc1,  const float* __restrict__ bin2,
              const float* __restrict__ bh2,  const float* __restrict__ bc1,
              unsigned short* __restrict__ wsb, unsigned short* __restrict__ wcf,
              float* __restrict__ b21, float* __restrict__ bce)
{
    __shared__ float sh[14400];
    const int blk = blockIdx.x, t = threadIdx.x;

    if (blk < 3) {
        float* C = sh + 4096;
        if (blk == 0) {
            for (int i = t; i < 1024; i += 256)
                *(float4*)&C[i * 4] = ldg4(win1 + i * 4);
            __syncthreads();
        } else {
            const float* A2 = (blk == 1) ? win2 : wh2;
            const float* bb = (blk == 1) ? bin2 : bh2;
            float* Bm    = sh;
            float* A2lds = sh + 8192;
            for (int i = t; i < 1024; i += 256)
                *(float4*)&Bm[i * 4] = ldg4(wh1 + i * 4);
            for (int i = t; i < 4096; i += 256) {
                const int r = i >> 6, k = i & 63;
                A2lds[r * 65 + k] = A2[i];
            }
            __syncthreads();
            const int r = t >> 2, cb = (t & 3) * 16;
            float av[16];
            #pragma unroll
            for (int c = 0; c < 16; ++c) av[c] = 0.f;
            for (int k = 0; k < 64; ++k) {
                const float a = A2lds[r * 65 + k];
                const float4 w0 = *(const float4*)&Bm[k * 64 + cb];
                const float4 w1 = *(const float4*)&Bm[k * 64 + cb + 4];
                const float4 w2 = *(const float4*)&Bm[k * 64 + cb + 8];
                const float4 w3 = *(const float4*)&Bm[k * 64 + cb + 12];
                av[0]=fmaf(a,w0.x,av[0]); av[1]=fmaf(a,w0.y,av[1]); av[2]=fmaf(a,w0.z,av[2]); av[3]=fmaf(a,w0.w,av[3]);
                av[4]=fmaf(a,w1.x,av[4]); av[5]=fmaf(a,w1.y,av[5]); av[6]=fmaf(a,w1.z,av[6]); av[7]=fmaf(a,w1.w,av[7]);
                av[8]=fmaf(a,w2.x,av[8]); av[9]=fmaf(a,w2.y,av[9]); av[10]=fmaf(a,w2.z,av[10]); av[11]=fmaf(a,w2.w,av[11]);
                av[12]=fmaf(a,w3.x,av[12]); av[13]=fmaf(a,w3.y,av[13]); av[14]=fmaf(a,w3.z,av[14]); av[15]=fmaf(a,w3.w,av[15]);
            }
            #pragma unroll
            for (int c = 0; c < 16; ++c) C[r * 64 + cb + c] = av[c];
            if (t < 64) {
                float s = 0.f;
                for (int k = 0; k < 64; ++k) s = fmaf(bb[k], Bm[k * 64 + t], s);
                b21[(blk - 1) * 64 + t] = s;
            }
            __syncthreads();
        }
        unsigned short* hi = wsb + blk * 8192;
        unsigned short* lo = hi + 4096;
        for (int f = t; f < 512; f += 256) {
            const int s = f >> 8, n = (f >> 6) & 3, ll = f & 63;
            const int g = ll >> 4, col = n * 16 + (ll & 15);
            unsigned int uh[4], ul[4];
            #pragma unroll
            for (int j2 = 0; j2 < 4; ++j2) {
                const float a  = C[(s * 32 + g * 8 + j2 * 2)     * 64 + col];
                const float bq = C[(s * 32 + g * 8 + j2 * 2 + 1) * 64 + col];
                uh[j2] = pk2(a, bq);
                ul[j2] = pk2lo(a, bq, uh[j2]);
            }
            *(u32x4*)(hi + f * 8) = (u32x4){uh[0], uh[1], uh[2], uh[3]};
            *(u32x4*)(lo + f * 8) = (u32x4){ul[0], ul[1], ul[2], ul[3]};
        }
    } else if (blk < 15) {
        const int chunk = blk - 3;
        float* wc1c = sh;
        float* A2T  = sh + 6144;
        for (int i = t; i < 1536; i += 256) {
            const int row = i >> 3, q = i & 7;
            *(float4*)&wc1c[row * 32 + q * 4] = ldg4(wc1 + (size_t)row * C2DIM + chunk * 32 + q * 4);
        }
        for (int i = t; i < 8192; i += 256) {
            const int r = i >> 6, k = i & 63;
            const float v = (r < 64) ? win2[r * 64 + k] : wh2[(r - 64) * 64 + k];
            A2T[k * 129 + r] = v;
        }
        __syncthreads();
        float acc[32];
        if (t < 192) {
            const int R  = (t < 64) ? t : 64 + (t & 63);
            const int kb = (t >> 6) * 64;
            #pragma unroll
            for (int c = 0; c < 32; ++c) acc[c] = 0.f;
            for (int k = 0; k < 64; ++k) {
                const float a = A2T[k * 129 + R];
                const float* wr = &wc1c[(kb + k) * 32];
                #pragma unroll
                for (int c4 = 0; c4 < 8; ++c4) {
                    const float4 w = *(const float4*)&wr[c4 * 4];
                    acc[c4 * 4 + 0] = fmaf(a, w.x, acc[c4 * 4 + 0]);
                    acc[c4 * 4 + 1] = fmaf(a, w.y, acc[c4 * 4 + 1]);
                    acc[c4 * 4 + 2] = fmaf(a, w.z, acc[c4 * 4 + 2]);
                    acc[c4 * 4 + 3] = fmaf(a, w.w, acc[c4 * 4 + 3]);
                }
            }
        }
        __syncthreads();
        float* C2 = sh;
        if (t < 192) {
            #pragma unroll
            for (int c = 0; c < 32; ++c) C2[t * 33 + c] = acc[c];
        }
        __syncthreads();
        unsigned short* hi = wcf;
        unsigned short* lo = wcf + 73728;
        for (int i = t; i < 768; i += 256) {
            const int s = i / 128, rem = i % 128;
            const int nl = rem >> 6, ll = rem & 63;
            const int n = chunk * 2 + nl;
            const int e = (s * 24 + n) * 64 + ll;
            const int cl = nl * 16 + (ll & 15);
            const int k0 = s * 32 + (ll >> 4) * 8;
            unsigned int uh[4], ul[4];
            #pragma unroll
            for (int j2 = 0; j2 < 4; ++j2) {
                const float a  = C2[(k0 + j2 * 2)     * 33 + cl];
                const float bq = C2[(k0 + j2 * 2 + 1) * 33 + cl];
                uh[j2] = pk2(a, bq);
                ul[j2] = pk2lo(a, bq, uh[j2]);
            }
            *(u32x4*)(hi + e * 8) = (u32x4){uh[0], uh[1], uh[2], uh[3]};
            *(u32x4*)(lo + e * 8) = (u32x4){ul[0], ul[1], ul[2], ul[3]};
        }
    } else {
        for (int j = t; j < C2DIM; j += 256) {
            float s = 0.f;
            for (int k = 0; k < 64; ++k) {
                s = fmaf(bin2[k], wc1[(size_t)k * C2DIM + j], s);
                s = fmaf(bh2[k],  wc1[(size_t)(64 + k) * C2DIM + j], s);
                s = fmaf(bh2[k],  wc1[(size_t)(128 + k) * C2DIM + j], s);
            }
            bce[j] = bc1[j] + 32.0f * s;
        }
    }
}

// ==== main kernel: one WAVE = one graph; zero barriers; DPP LayerNorm ====
extern "C" __global__ void __launch_bounds__(256, 4)
gin_fused_kernel(const int* __restrict__ x, const int* __restrict__ los,
                 const int* __restrict__ eidx,
                 const float* __restrict__ emb,
                 const float* __restrict__ bin1,
                 const float* __restrict__ gin_g, const float* __restrict__ gin_b,
                 const float* __restrict__ bh1,
                 const float* __restrict__ gh_g, const float* __restrict__ gh_b,
                 const float* __restrict__ epsv,
                 const unsigned short* __restrict__ wsb,
                 const float* __restrict__ b21,
                 float* __restrict__ pooled_ws)
{
    __shared__ __align__(16) float S[4 * GWORDS];   // per-wave private region (9216 B)

    const int t  = threadIdx.x;
    const int wv = t >> 6;
    const int l  = t & 63;
    const int b  = blockIdx.x * 4 + wv;
    float* scr = &S[wv * GWORDS];                   // fp32 H [32][68] (aliased by pair buf)
    unsigned int* bp = (unsigned int*)scr;          // pair buf: hi [64 col][18], lo at +1152
    const int lc = l & 15;
    const int lg = l >> 4;

    // ---- histogram (wave-local; cnt aliases scr) ----
    int* cnt = (int*)scr;
    #pragma unroll
    for (int i = 0; i < 16; ++i) cnt[l + 64 * i] = 0;
    {
        const int ebase = b * EPG;
        const int goff  = b * NNODE;
        #pragma unroll
        for (int i = 0; i < 8; ++i) {
            const int e = ebase + l + 64 * i;
            const int sN = eidx[e] - goff;
            const int dN = eidx[NBATCH * EPG + e] - goff;
            atomicAdd(&cnt[dN * NNODE + sN], 1);
        }
    }
    // ---- adjacency A-frags (hi only; counts exact in bf16) ----
    u32x4 adjf[2];
    #pragma unroll
    for (int m = 0; m < 2; ++m) {
        const int4 a0 = *(const int4*)&cnt[(m * 16 + lc) * NNODE + lg * 8];
        const int4 a1 = *(const int4*)&cnt[(m * 16 + lc) * NNODE + lg * 8 + 4];
        adjf[m] = (u32x4){ pk2((float)a0.x, (float)a0.y), pk2((float)a0.z, (float)a0.w),
                           pk2((float)a1.x, (float)a1.y), pk2((float)a1.z, (float)a1.w) };
    }
    // ---- embedding -> scr (in-order LDS pipe: WAR vs cnt reads safe) ----
    {
        const int node = l >> 1;
        const int idx = (node < NNODE - 1) ? x[b * (NNODE - 1) + node] : los[b];
        const float* er = emb + ((size_t)(node * NVOCAB + idx)) * DIM + (l & 1) * 32;
        float* sr = scr + node * HSTR + (l & 1) * 32;
        #pragma unroll
        for (int i = 0; i < 8; ++i)
            *reinterpret_cast<float4*>(sr + i * 4) = ldg4(er + i * 4);
    }

    f32x4 acc[2][4];
    u32x4 azh[2][2], azl[2][2];

    for (int st = 0; st < 3; ++st) {
        const unsigned short* Wf = wsb + st * 8192;
        const float* bpost = st ? bh1  : bin1;
        const float* Gg    = st ? gh_g : gin_g;
        const float* Gb    = st ? gh_b : gin_b;
        const float sc = 1.0f + epsv[st];

        // stage input -> scr fp32 (stage0: embeddings already there)
        if (st) {
            #pragma unroll
            for (int m = 0; m < 2; ++m)
                #pragma unroll
                for (int n = 0; n < 4; ++n)
                    #pragma unroll
                    for (int r = 0; r < 4; ++r)
                        scr[(m * 16 + lg * 4 + r) * HSTR + n * 16 + lc] = acc[m][n][r];
        }
        // A-frags of input (genuine transpose through LDS)
        #pragma unroll
        for (int m = 0; m < 2; ++m)
            #pragma unroll
            for (int s = 0; s < 2; ++s) {
                const float4 v0 = *(const float4*)&scr[(m * 16 + lc) * HSTR + s * 32 + lg * 8];
                const float4 v1 = *(const float4*)&scr[(m * 16 + lc) * HSTR + s * 32 + lg * 8 + 4];
                azh[m][s] = (u32x4){ pk2(v0.x,v0.y), pk2(v0.z,v0.w), pk2(v1.x,v1.y), pk2(v1.z,v1.w) };
                azl[m][s] = (u32x4){ pk2lo(v0.x,v0.y,azh[m][s][0]), pk2lo(v0.z,v0.w,azh[m][s][1]),
                                     pk2lo(v1.x,v1.y,azh[m][s][2]), pk2lo(v1.z,v1.w,azh[m][s][3]) };
            }
        // v = input @ W + b_pre
        #pragma unroll
        for (int n = 0; n < 4; ++n) {
            const float bpv = st ? b21[(st - 1) * 64 + n * 16 + lc] : 0.f;
            #pragma unroll
            for (int m = 0; m < 2; ++m)
                acc[m][n] = (f32x4){bpv, bpv, bpv, bpv};
        }
        #pragma unroll
        for (int n = 0; n < 4; ++n)
            #pragma unroll
            for (int s = 0; s < 2; ++s) {
                const u32x4 wh = *(const u32x4*)(Wf +        ((s * 4 + n) * 64 + l) * 8);
                const u32x4 wl = *(const u32x4*)(Wf + 4096 + ((s * 4 + n) * 64 + l) * 8);
                #pragma unroll
                for (int m = 0; m < 2; ++m) {
                    acc[m][n] = MFMA(azh[m][s], wh, acc[m][n]);
                    acc[m][n] = MFMA(azh[m][s], wl, acc[m][n]);
                    acc[m][n] = MFMA(azl[m][s], wh, acc[m][n]);
                }
            }
        // v-pairs (bf16 hi/lo) -> pair buf DIRECTLY from registers.
        #pragma unroll
        for (int m = 0; m < 2; ++m)
            #pragma unroll
            for (int n = 0; n < 4; ++n) {
                const int col = n * 16 + lc;
                const int p0  = m * 8 + lg * 2;
                uint2 h2, l2;
                h2.x = pk2(acc[m][n][0], acc[m][n][1]);
                h2.y = pk2(acc[m][n][2], acc[m][n][3]);
                l2.x = pk2lo(acc[m][n][0], acc[m][n][1], h2.x);
                l2.y = pk2lo(acc[m][n][2], acc[m][n][3], h2.y);
                *(uint2*)&bp[col * 18 + p0]        = h2;
                *(uint2*)&bp[1152 + col * 18 + p0] = l2;
            }
        // in-place seeds: acc = sc*v + b_post
        #pragma unroll
        for (int n = 0; n < 4; ++n) {
            const float bq = bpost[n * 16 + lc];
            #pragma unroll
            for (int m = 0; m < 2; ++m)
                #pragma unroll
                for (int r = 0; r < 4; ++r)
                    acc[m][n][r] = sc * acc[m][n][r] + bq;
        }
        // agg: acc += A @ v — B-frags are raw b64 reads, zero conversion
        #pragma unroll
        for (int n = 0; n < 4; ++n) {
            const int base = (n * 16 + lc) * 18 + lg * 4;
            const uint2 ha = *(const uint2*)&bp[base];
            const uint2 hb = *(const uint2*)&bp[base + 2];
            const uint2 la = *(const uint2*)&bp[1152 + base];
            const uint2 lb = *(const uint2*)&bp[1152 + base + 2];
            const u32x4 hh = (u32x4){ha.x, ha.y, hb.x, hb.y};
            const u32x4 hl = (u32x4){la.x, la.y, lb.x, lb.y};
            #pragma unroll
            for (int m = 0; m < 2; ++m) {
                acc[m][n] = MFMA(adjf[m], hh, acc[m][n]);
                acc[m][n] = MFMA(adjf[m], hl, acc[m][n]);
            }
        }
        // LayerNorm + relu — cross-lane sums via DPP rotation butterfly (no LDS pipe)
        {
            float gg[4], gb[4];
            #pragma unroll
            for (int n = 0; n < 4; ++n) { gg[n] = Gg[n * 16 + lc]; gb[n] = Gb[n * 16 + lc]; }
            #pragma unroll
            for (int m = 0; m < 2; ++m)
                #pragma unroll
                for (int r = 0; r < 4; ++r) {
                    float a0 = acc[m][0][r], a1 = acc[m][1][r];
                    float a2 = acc[m][2][r], a3 = acc[m][3][r];
                    const float s1 = rowsum16(a0 + a1 + a2 + a3);
                    const float s2 = rowsum16(a0 * a0 + a1 * a1 + a2 * a2 + a3 * a3);
                    const float mu  = s1 * (1.0f / 64.0f);
                    const float var = s2 * (1.0f / 64.0f) - mu * mu;
                    const float inv = rsqrtf(var + LN_EPS);
                    acc[m][0][r] = fmaxf((a0 - mu) * inv * gg[0] + gb[0], 0.f);
                    acc[m][1][r] = fmaxf((a1 - mu) * inv * gg[1] + gb[1], 0.f);
                    acc[m][2][r] = fmaxf((a2 - mu) * inv * gg[2] + gb[2], 0.f);
                    acc[m][3][r] = fmaxf((a3 - mu) * inv * gg[3] + gb[3], 0.f);
                }
        }
        // cs[st] = colsum(y) -> workspace
        #pragma unroll
        for (int n = 0; n < 4; ++n) {
            float p = 0.f;
            #pragma unroll
            for (int m = 0; m < 2; ++m)
                #pragma unroll
                for (int r = 0; r < 4; ++r) p += acc[m][n][r];
            p += __shfl_xor(p, 16);
            p += __shfl_xor(p, 32);
            if (l < 16)
                pooled_ws[(size_t)b * CDIM + st * DIM + n * 16 + l] = p;
        }
    }
}

// ---- classifier: 8 waves (2/SIMD) for latency hiding; 3 n-tiles per wave ----
extern "C" __global__ void __launch_bounds__(512)
classifier_kernel(const float* __restrict__ pooled_ws,
                  const unsigned short* __restrict__ wcf,
                  const float* __restrict__ bce, const float* __restrict__ wc2,
                  const float* __restrict__ bc2, float* __restrict__ out)
{
    #define PSTR 196
    __shared__ __align__(16) float P[16 * PSTR];
    __shared__ __align__(16) unsigned int afh[6 * 64 * 4];
    __shared__ __align__(16) unsigned int afl[6 * 64 * 4];
    __shared__ float rsum[8][16];

    const int b = blockIdx.x;
    const int t = threadIdx.x;
    const int l = t & 63;
    const int w = t >> 6;          // 0..7
    const unsigned short* wclo = wcf + 73728;

    for (int i = t; i < 16 * 48; i += 512) {
        const int row = i / 48, q = i % 48;
        const float4 v = ldg4(pooled_ws + ((size_t)(b * 16 + row)) * CDIM + q * 4);
        *reinterpret_cast<float4*>(&P[row * PSTR + q * 4]) = v;
    }
    __syncthreads();

    for (int e = t; e < 6 * 64; e += 512) {
        const int s = e >> 6, ll = e & 63;
        const int row = ll & 15;
        const int k0 = s * 32 + (ll >> 4) * 8;
        const float4 v0 = *reinterpret_cast<const float4*>(&P[row * PSTR + k0]);
        const float4 v1 = *reinterpret_cast<const float4*>(&P[row * PSTR + k0 + 4]);
        const float y[8] = { v0.x, v0.y, v0.z, v0.w, v1.x, v1.y, v1.z, v1.w };
        unsigned int uh[4], ul[4];
        #pragma unroll
        for (int j2 = 0; j2 < 4; ++j2) {
            uh[j2] = pk2(y[j2 * 2], y[j2 * 2 + 1]);
            ul[j2] = pk2lo(y[j2 * 2], y[j2 * 2 + 1], uh[j2]);
        }
        *reinterpret_cast<u32x4*>(&afh[e * 4]) = (u32x4){uh[0], uh[1], uh[2], uh[3]};
        *reinterpret_cast<u32x4*>(&afl[e * 4]) = (u32x4){ul[0], ul[1], ul[2], ul[3]};
    }
    __syncthreads();

    float part[4] = {0.f, 0.f, 0.f, 0.f};
    for (int nt = 0; nt < 3; ++nt) {
        const int n = w * 3 + nt;
        f32x4 acc = {0.f, 0.f, 0.f, 0.f};
        #pragma unroll
        for (int s = 0; s < 6; ++s) {
            const u32x4 ah = *(const u32x4*)&afh[(s * 64 + l) * 4];
            const u32x4 al = *(const u32x4*)&afl[(s * 64 + l) * 4];
            const u32x4 bh = *(const u32x4*)&wcf [((s * 24 + n) * 64 + l) * 8];
            const u32x4 bl = *(const u32x4*)&wclo[((s * 24 + n) * 64 + l) * 8];
            acc = MFMA(ah, bh, acc);
            acc = MFMA(ah, bl, acc);
            acc = MFMA(al, bh, acc);
        }
        const int col = n * 16 + (l & 15);
        const float bias = bce[col], w2 = wc2[col];
        #pragma unroll
        for (int r = 0; r < 4; ++r)
            part[r] += fmaxf(acc[r] + bias, 0.f) * w2;
    }
    #pragma unroll
    for (int r = 0; r < 4; ++r) {
        part[r] += __shfl_xor(part[r], 1);
        part[r] += __shfl_xor(part[r], 2);
        part[r] += __shfl_xor(part[r], 4);
        part[r] += __shfl_xor(part[r], 8);
    }
    if ((l & 15) == 0) {
        const int g = l >> 4;
        #pragma unroll
        for (int r = 0; r < 4; ++r) rsum[w][g * 4 + r] = part[r];
    }
    __syncthreads();
    if (t < 16) {
        float s = bc2[0];
        #pragma unroll
        for (int w2i = 0; w2i < 8; ++w2i) s += rsum[w2i][t];
        out[b * 16 + t] = s;
    }
}

extern "C" void kernel_launch(void* const* d_in, const int* in_sizes, int n_in,
                              void* d_out, int out_size, void* d_ws, size_t ws_size,
                              hipStream_t stream)
{
    const int*   x     = (const int*)d_in[0];
    const int*   los   = (const int*)d_in[1];
    const int*   eidx  = (const int*)d_in[2];
    const float* emb   = (const float*)d_in[3];
    const float* win1  = (const float*)d_in[4];
    const float* bin1  = (const float*)d_in[5];
    const float* gin_g = (const float*)d_in[6];
    const float* gin_b = (const float*)d_in[7];
    const float* win2  = (const float*)d_in[8];
    const float* bin2  = (const float*)d_in[9];
    const float* wh1   = (const float*)d_in[10];
    const float* bh1   = (const float*)d_in[11];
    const float* gh_g  = (const float*)d_in[12];
    const float* gh_b  = (const float*)d_in[13];
    const float* wh2   = (const float*)d_in[14];
    const float* bh2   = (const float*)d_in[15];
    const float* epsv  = (const float*)d_in[16];
    const float* wc1   = (const float*)d_in[17];
    const float* bc1   = (const float*)d_in[18];
    const float* wc2   = (const float*)d_in[19];
    const float* bc2   = (const float*)d_in[20];
    float* out = (float*)d_out;

    unsigned short* wsb = (unsigned short*)((char*)d_ws + WS_WFRAG_OFF);
    float*          b21 = (float*)((char*)d_ws + WS_B21_OFF);
    unsigned short* wcf = (unsigned short*)((char*)d_ws + WS_WCF_OFF);
    float*          bce = (float*)((char*)d_ws + WS_BCE_OFF);
    float*          cs  = (float*)((char*)d_ws + WS_POOL_OFF);

    hipLaunchKernelGGL(prep_w_kernel, dim3(16), dim3(256), 0, stream,
                       win1, win2, wh1, wh2, wc1, bin2, bh2, bc1,
                       wsb, wcf, b21, bce);
    hipLaunchKernelGGL(gin_fused_kernel, dim3(NBATCH / 4), dim3(256), 0, stream,
                       x, los, eidx, emb, bin1, gin_g, gin_b,
                       bh1, gh_g, gh_b, epsv,
                       (const unsigned short*)wsb, (const float*)b21, cs);
    hipLaunchKernelGGL(classifier_kernel, dim3(NBATCH / 16), dim3(512), 0, stream,
                       (const float*)cs, (const unsigned short*)wcf,
                       (const float*)bce, wc2, bc2, out);
}

// Round 15
// 50.054 us; speedup vs baseline: 1.3743x; 1.0822x over previous
//
#include <hip/hip_runtime.h>

#define NBATCH 4096
#define NNODE  32
#define NVOCAB 100
#define DIM    64
#define EPG    512
#define HSTR   68      // padded fp32 LDS row stride
#define LN_EPS 1e-5f
#define CDIM   192
#define C2DIM  384
#define GWORDS 2304    // per-graph LDS words: max(32*68 fp32, 2*64*18 pair-words)

// workspace layout (bytes)
#define WS_WFRAG_OFF   0         // 3 x 16384 B stage-W frags (Win1[unused], Win2@Wh1, Wh2@Wh1)
#define WS_B21_OFF     49152     // 128 floats: b21a(64), b21b(64)
#define WS_WCF_OFF     65536     // Wc_eff frags: hi 147456 + lo 147456
#define WS_BCE_OFF     360448    // bc_eff: 384 floats
#define WS_POOL_OFF    364544    // cs 4096*192 f32 = 3145728
#define WS_EMBW_OFF    3510272   // embW = emb@win1: 3200 x 64 f32 = 819200 B

typedef float          f32x4  __attribute__((ext_vector_type(4)));
typedef unsigned int   u32x4  __attribute__((ext_vector_type(4)));
typedef __bf16         bf16x8 __attribute__((ext_vector_type(8)));

__device__ __forceinline__ float4 ldg4(const float* __restrict__ p) {
    return *reinterpret_cast<const float4*>(p);
}
__device__ __forceinline__ unsigned short f2bf(float f) {
    return __builtin_bit_cast(unsigned short, static_cast<__bf16>(f));
}
__device__ __forceinline__ float bf2f(unsigned short h) {
    return static_cast<float>(__builtin_bit_cast(__bf16, h));
}
__device__ __forceinline__ unsigned int pk2(float a, float b) {
    return (unsigned int)f2bf(a) | ((unsigned int)f2bf(b) << 16);
}
__device__ __forceinline__ unsigned int pk2lo(float a, float b, unsigned int hi) {
    const float ra = a - bf2f((unsigned short)(hi & 0xffff));
    const float rb = b - bf2f((unsigned short)(hi >> 16));
    return pk2(ra, rb);
}
__device__ __forceinline__ bf16x8 as_bf(u32x4 v) {
    return __builtin_bit_cast(bf16x8, v);
}
// sum across the 16 lanes of a DPP row via rotation butterfly — pure VALU
__device__ __forceinline__ float rowsum16(float v) {
    int x = __builtin_bit_cast(int, v);
    v += __builtin_bit_cast(float, __builtin_amdgcn_update_dpp(0, x, 0x128, 0xF, 0xF, false)); // ror:8
    x = __builtin_bit_cast(int, v);
    v += __builtin_bit_cast(float, __builtin_amdgcn_update_dpp(0, x, 0x124, 0xF, 0xF, false)); // ror:4
    x = __builtin_bit_cast(int, v);
    v += __builtin_bit_cast(float, __builtin_amdgcn_update_dpp(0, x, 0x122, 0xF, 0xF, false)); // ror:2
    x = __builtin_bit_cast(int, v);
    v += __builtin_bit_cast(float, __builtin_amdgcn_update_dpp(0, x, 0x121, 0xF, 0xF, false)); // ror:1
    return v;
}
#define MFMA(a, b, c) __builtin_amdgcn_mfma_f32_16x16x32_bf16(as_bf(a), as_bf(b), (c), 0, 0, 0)

// ---- pre-kernel: blocks 0..2 stage-W frags, 3..14 Wc_eff, 15 bc_eff, 16..115 embW ----
extern "C" __global__ void __launch_bounds__(256)
prep_w_kernel(const float* __restrict__ win1, const float* __restrict__ win2,
              const float* __restrict__ wh1,  const float* __restrict__ wh2,
              const float* __restrict__ wc1,  const float* __restrict__ bin2,
              const float* __restrict__ bh2,  const float* __restrict__ bc1,
              const float* __restrict__ emb,
              unsigned short* __restrict__ wsb, unsigned short* __restrict__ wcf,
              float* __restrict__ b21, float* __restrict__ bce,
              float* __restrict__ embw)
{
    __shared__ float sh[14400];
    const int blk = blockIdx.x, t = threadIdx.x;

    if (blk < 3) {
        float* C = sh + 4096;
        if (blk == 0) {
            for (int i = t; i < 1024; i += 256)
                *(float4*)&C[i * 4] = ldg4(win1 + i * 4);
            __syncthreads();
        } else {
            const float* A2 = (blk == 1) ? win2 : wh2;
            const float* bb = (blk == 1) ? bin2 : bh2;
            float* Bm    = sh;
            float* A2lds = sh + 8192;
            for (int i = t; i < 1024; i += 256)
                *(float4*)&Bm[i * 4] = ldg4(wh1 + i * 4);
            for (int i = t; i < 4096; i += 256) {
                const int r = i >> 6, k = i & 63;
                A2lds[r * 65 + k] = A2[i];
            }
            __syncthreads();
            const int r = t >> 2, cb = (t & 3) * 16;
            float av[16];
            #pragma unroll
            for (int c = 0; c < 16; ++c) av[c] = 0.f;
            for (int k = 0; k < 64; ++k) {
                const float a = A2lds[r * 65 + k];
                const float4 w0 = *(const float4*)&Bm[k * 64 + cb];
                const float4 w1 = *(const float4*)&Bm[k * 64 + cb + 4];
                const float4 w2 = *(const float4*)&Bm[k * 64 + cb + 8];
                const float4 w3 = *(const float4*)&Bm[k * 64 + cb + 12];
                av[0]=fmaf(a,w0.x,av[0]); av[1]=fmaf(a,w0.y,av[1]); av[2]=fmaf(a,w0.z,av[2]); av[3]=fmaf(a,w0.w,av[3]);
                av[4]=fmaf(a,w1.x,av[4]); av[5]=fmaf(a,w1.y,av[5]); av[6]=fmaf(a,w1.z,av[6]); av[7]=fmaf(a,w1.w,av[7]);
                av[8]=fmaf(a,w2.x,av[8]); av[9]=fmaf(a,w2.y,av[9]); av[10]=fmaf(a,w2.z,av[10]); av[11]=fmaf(a,w2.w,av[11]);
                av[12]=fmaf(a,w3.x,av[12]); av[13]=fmaf(a,w3.y,av[13]); av[14]=fmaf(a,w3.z,av[14]); av[15]=fmaf(a,w3.w,av[15]);
            }
            #pragma unroll
            for (int c = 0; c < 16; ++c) C[r * 64 + cb + c] = av[c];
            if (t < 64) {
                float s = 0.f;
                for (int k = 0; k < 64; ++k) s = fmaf(bb[k], Bm[k * 64 + t], s);
                b21[(blk - 1) * 64 + t] = s;
            }
            __syncthreads();
        }
        unsigned short* hi = wsb + blk * 8192;
        unsigned short* lo = hi + 4096;
        for (int f = t; f < 512; f += 256) {
            const int s = f >> 8, n = (f >> 6) & 3, ll = f & 63;
            const int g = ll >> 4, col = n * 16 + (ll & 15);
            unsigned int uh[4], ul[4];
            #pragma unroll
            for (int j2 = 0; j2 < 4; ++j2) {
                const float a  = C[(s * 32 + g * 8 + j2 * 2)     * 64 + col];
                const float bq = C[(s * 32 + g * 8 + j2 * 2 + 1) * 64 + col];
                uh[j2] = pk2(a, bq);
                ul[j2] = pk2lo(a, bq, uh[j2]);
            }
            *(u32x4*)(hi + f * 8) = (u32x4){uh[0], uh[1], uh[2], uh[3]};
            *(u32x4*)(lo + f * 8) = (u32x4){ul[0], ul[1], ul[2], ul[3]};
        }
    } else if (blk < 15) {
        const int chunk = blk - 3;
        float* wc1c = sh;
        float* A2T  = sh + 6144;
        for (int i = t; i < 1536; i += 256) {
            const int row = i >> 3, q = i & 7;
            *(float4*)&wc1c[row * 32 + q * 4] = ldg4(wc1 + (size_t)row * C2DIM + chunk * 32 + q * 4);
        }
        for (int i = t; i < 8192; i += 256) {
            const int r = i >> 6, k = i & 63;
            const float v = (r < 64) ? win2[r * 64 + k] : wh2[(r - 64) * 64 + k];
            A2T[k * 129 + r] = v;
        }
        __syncthreads();
        float acc[32];
        if (t < 192) {
            const int R  = (t < 64) ? t : 64 + (t & 63);
            const int kb = (t >> 6) * 64;
            #pragma unroll
            for (int c = 0; c < 32; ++c) acc[c] = 0.f;
            for (int k = 0; k < 64; ++k) {
                const float a = A2T[k * 129 + R];
                const float* wr = &wc1c[(kb + k) * 32];
                #pragma unroll
                for (int c4 = 0; c4 < 8; ++c4) {
                    const float4 w = *(const float4*)&wr[c4 * 4];
                    acc[c4 * 4 + 0] = fmaf(a, w.x, acc[c4 * 4 + 0]);
                    acc[c4 * 4 + 1] = fmaf(a, w.y, acc[c4 * 4 + 1]);
                    acc[c4 * 4 + 2] = fmaf(a, w.z, acc[c4 * 4 + 2]);
                    acc[c4 * 4 + 3] = fmaf(a, w.w, acc[c4 * 4 + 3]);
                }
            }
        }
        __syncthreads();
        float* C2 = sh;
        if (t < 192) {
            #pragma unroll
            for (int c = 0; c < 32; ++c) C2[t * 33 + c] = acc[c];
        }
        __syncthreads();
        unsigned short* hi = wcf;
        unsigned short* lo = wcf + 73728;
        for (int i = t; i < 768; i += 256) {
            const int s = i / 128, rem = i % 128;
            const int nl = rem >> 6, ll = rem & 63;
            const int n = chunk * 2 + nl;
            const int e = (s * 24 + n) * 64 + ll;
            const int cl = nl * 16 + (ll & 15);
            const int k0 = s * 32 + (ll >> 4) * 8;
            unsigned int uh[4], ul[4];
            #pragma unroll
            for (int j2 = 0; j2 < 4; ++j2) {
                const float a  = C2[(k0 + j2 * 2)     * 33 + cl];
                const float bq = C2[(k0 + j2 * 2 + 1) * 33 + cl];
                uh[j2] = pk2(a, bq);
                ul[j2] = pk2lo(a, bq, uh[j2]);
            }
            *(u32x4*)(hi + e * 8) = (u32x4){uh[0], uh[1], uh[2], uh[3]};
            *(u32x4*)(lo + e * 8) = (u32x4){ul[0], ul[1], ul[2], ul[3]};
        }
    } else if (blk == 15) {
        for (int j = t; j < C2DIM; j += 256) {
            float s = 0.f;
            for (int k = 0; k < 64; ++k) {
                s = fmaf(bin2[k], wc1[(size_t)k * C2DIM + j], s);
                s = fmaf(bh2[k],  wc1[(size_t)(64 + k) * C2DIM + j], s);
                s = fmaf(bh2[k],  wc1[(size_t)(128 + k) * C2DIM + j], s);
            }
            bce[j] = bc1[j] + 32.0f * s;
        }
    } else {
        // ---- embW = emb_tables @ win1 : blocks 16..115, 32 rows each ----
        const int rbase = (blk - 16) * 32;
        float* W1l = sh;            // [64][64]
        float* er  = sh + 4096;     // [32][65]
        for (int i = t; i < 1024; i += 256)
            *(float4*)&W1l[i * 4] = ldg4(win1 + i * 4);
        for (int i = t; i < 512; i += 256) {   // 32 rows x 64 cols / 4
            const int rr = i >> 4, q = i & 15;
            const float4 v = ldg4(emb + (size_t)(rbase + rr) * 64 + q * 4);
            er[rr * 65 + q * 4 + 0] = v.x;
            er[rr * 65 + q * 4 + 1] = v.y;
            er[rr * 65 + q * 4 + 2] = v.z;
            er[rr * 65 + q * 4 + 3] = v.w;
        }
        __syncthreads();
        const int rr = t >> 3, cg = (t & 7) * 8;
        float a8[8];
        #pragma unroll
        for (int c = 0; c < 8; ++c) a8[c] = 0.f;
        for (int k = 0; k < 64; ++k) {
            const float a = er[rr * 65 + k];
            const float4 w0 = *(const float4*)&W1l[k * 64 + cg];
            const float4 w1 = *(const float4*)&W1l[k * 64 + cg + 4];
            a8[0] = fmaf(a, w0.x, a8[0]); a8[1] = fmaf(a, w0.y, a8[1]);
            a8[2] = fmaf(a, w0.z, a8[2]); a8[3] = fmaf(a, w0.w, a8[3]);
            a8[4] = fmaf(a, w1.x, a8[4]); a8[5] = fmaf(a, w1.y, a8[5]);
            a8[6] = fmaf(a, w1.z, a8[6]); a8[7] = fmaf(a, w1.w, a8[7]);
        }
        float* outr = embw + (size_t)(rbase + rr) * 64 + cg;
        *(float4*)outr       = (float4){a8[0], a8[1], a8[2], a8[3]};
        *(float4*)(outr + 4) = (float4){a8[4], a8[5], a8[6], a8[7]};
    }
}

// ==== main kernel: one WAVE = one graph; zero barriers; stage0 mm precomputed ====
extern "C" __global__ void __launch_bounds__(256, 4)
gin_fused_kernel(const int* __restrict__ x, const int* __restrict__ los,
                 const int* __restrict__ eidx,
                 const float* __restrict__ embw,
                 const float* __restrict__ bin1,
                 const float* __restrict__ gin_g, const float* __restrict__ gin_b,
                 const float* __restrict__ bh1,
                 const float* __restrict__ gh_g, const float* __restrict__ gh_b,
                 const float* __restrict__ epsv,
                 const unsigned short* __restrict__ wsb,
                 const float* __restrict__ b21,
                 float* __restrict__ pooled_ws)
{
    __shared__ __align__(16) float S[4 * GWORDS];   // per-wave private region (9216 B)

    const int t  = threadIdx.x;
    const int wv = t >> 6;
    const int l  = t & 63;
    const int b  = blockIdx.x * 4 + wv;
    float* scr = &S[wv * GWORDS];                   // fp32 y [32][68] (aliased by pair buf)
    unsigned int* bp = (unsigned int*)scr;          // pair buf: hi [64 col][18], lo at +1152
    const int lc = l & 15;
    const int lg = l >> 4;

    // ---- histogram (wave-local; cnt aliases scr) ----
    int* cnt = (int*)scr;
    #pragma unroll
    for (int i = 0; i < 16; ++i) cnt[l + 64 * i] = 0;
    {
        const int ebase = b * EPG;
        const int goff  = b * NNODE;
        #pragma unroll
        for (int i = 0; i < 8; ++i) {
            const int e = ebase + l + 64 * i;
            const int sN = eidx[e] - goff;
            const int dN = eidx[NBATCH * EPG + e] - goff;
            atomicAdd(&cnt[dN * NNODE + sN], 1);
        }
    }
    // ---- adjacency A-frags (hi only; counts exact in bf16) ----
    u32x4 adjf[2];
    #pragma unroll
    for (int m = 0; m < 2; ++m) {
        const int4 a0 = *(const int4*)&cnt[(m * 16 + lc) * NNODE + lg * 8];
        const int4 a1 = *(const int4*)&cnt[(m * 16 + lc) * NNODE + lg * 8 + 4];
        adjf[m] = (u32x4){ pk2((float)a0.x, (float)a0.y), pk2((float)a0.z, (float)a0.w),
                           pk2((float)a1.x, (float)a1.y), pk2((float)a1.z, (float)a1.w) };
    }

    f32x4 acc[2][4];

    for (int st = 0; st < 3; ++st) {
        const float* bpost = st ? bh1  : bin1;
        const float* Gg    = st ? gh_g : gin_g;
        const float* Gb    = st ? gh_b : gin_b;
        const float sc = 1.0f + epsv[st];

        if (st == 0) {
            // ---- v = H @ Win1 directly from precomputed embW (L2-resident) ----
            #pragma unroll
            for (int m = 0; m < 2; ++m)
                #pragma unroll
                for (int r = 0; r < 4; ++r) {
                    const int node = m * 16 + lg * 4 + r;
                    const int idx = (node < NNODE - 1) ? x[b * (NNODE - 1) + node] : los[b];
                    const float* vr = embw + ((size_t)(node * NVOCAB + idx)) * DIM + lc;
                    #pragma unroll
                    for (int n = 0; n < 4; ++n)
                        acc[m][n][r] = vr[n * 16];
                }
        } else {
            const unsigned short* Wf = wsb + st * 8192;
            // y -> scr fp32 (prev stage output in acc)
            #pragma unroll
            for (int m = 0; m < 2; ++m)
                #pragma unroll
                for (int n = 0; n < 4; ++n)
                    #pragma unroll
                    for (int r = 0; r < 4; ++r)
                        scr[(m * 16 + lg * 4 + r) * HSTR + n * 16 + lc] = acc[m][n][r];
            // A-frags of y (transpose through LDS)
            u32x4 azh[2][2], azl[2][2];
            #pragma unroll
            for (int m = 0; m < 2; ++m)
                #pragma unroll
                for (int s = 0; s < 2; ++s) {
                    const float4 v0 = *(const float4*)&scr[(m * 16 + lc) * HSTR + s * 32 + lg * 8];
                    const float4 v1 = *(const float4*)&scr[(m * 16 + lc) * HSTR + s * 32 + lg * 8 + 4];
                    azh[m][s] = (u32x4){ pk2(v0.x,v0.y), pk2(v0.z,v0.w), pk2(v1.x,v1.y), pk2(v1.z,v1.w) };
                    azl[m][s] = (u32x4){ pk2lo(v0.x,v0.y,azh[m][s][0]), pk2lo(v0.z,v0.w,azh[m][s][1]),
                                         pk2lo(v1.x,v1.y,azh[m][s][2]), pk2lo(v1.z,v1.w,azh[m][s][3]) };
                }
            // v = y @ W21 + b21
            #pragma unroll
            for (int n = 0; n < 4; ++n) {
                const float bpv = b21[(st - 1) * 64 + n * 16 + lc];
                #pragma unroll
                for (int m = 0; m < 2; ++m)
                    acc[m][n] = (f32x4){bpv, bpv, bpv, bpv};
            }
            #pragma unroll
            for (int n = 0; n < 4; ++n)
                #pragma unroll
                for (int s = 0; s < 2; ++s) {
                    const u32x4 wh = *(const u32x4*)(Wf +        ((s * 4 + n) * 64 + l) * 8);
                    const u32x4 wl = *(const u32x4*)(Wf + 4096 + ((s * 4 + n) * 64 + l) * 8);
                    #pragma unroll
                    for (int m = 0; m < 2; ++m) {
                        acc[m][n] = MFMA(azh[m][s], wh, acc[m][n]);
                        acc[m][n] = MFMA(azh[m][s], wl, acc[m][n]);
                        acc[m][n] = MFMA(azl[m][s], wh, acc[m][n]);
                    }
                }
        }
        // v-pairs (bf16 hi/lo) -> pair buf DIRECTLY from registers.
        #pragma unroll
        for (int m = 0; m < 2; ++m)
            #pragma unroll
            for (int n = 0; n < 4; ++n) {
                const int col = n * 16 + lc;
                const int p0  = m * 8 + lg * 2;
                uint2 h2, l2;
                h2.x = pk2(acc[m][n][0], acc[m][n][1]);
                h2.y = pk2(acc[m][n][2], acc[m][n][3]);
                l2.x = pk2lo(acc[m][n][0], acc[m][n][1], h2.x);
                l2.y = pk2lo(acc[m][n][2], acc[m][n][3], h2.y);
                *(uint2*)&bp[col * 18 + p0]        = h2;
                *(uint2*)&bp[1152 + col * 18 + p0] = l2;
            }
        // in-place seeds: acc = sc*v + b_post
        #pragma unroll
        for (int n = 0; n < 4; ++n) {
            const float bq = bpost[n * 16 + lc];
            #pragma unroll
            for (int m = 0; m < 2; ++m)
                #pragma unroll
                for (int r = 0; r < 4; ++r)
                    acc[m][n][r] = sc * acc[m][n][r] + bq;
        }
        // agg: acc += A @ v — raw b64 reads, zero conversion
        #pragma unroll
        for (int n = 0; n < 4; ++n) {
            const int base = (n * 16 + lc) * 18 + lg * 4;
            const uint2 ha = *(const uint2*)&bp[base];
            const uint2 hb = *(const uint2*)&bp[base + 2];
            const uint2 la = *(const uint2*)&bp[1152 + base];
            const uint2 lb = *(const uint2*)&bp[1152 + base + 2];
            const u32x4 hh = (u32x4){ha.x, ha.y, hb.x, hb.y};
            const u32x4 hl = (u32x4){la.x, la.y, lb.x, lb.y};
            #pragma unroll
            for (int m = 0; m < 2; ++m) {
                acc[m][n] = MFMA(adjf[m], hh, acc[m][n]);
                acc[m][n] = MFMA(adjf[m], hl, acc[m][n]);
            }
        }
        // LayerNorm + relu — cross-lane sums via DPP rotation butterfly
        {
            float gg[4], gb[4];
            #pragma unroll
            for (int n = 0; n < 4; ++n) { gg[n] = Gg[n * 16 + lc]; gb[n] = Gb[n * 16 + lc]; }
            #pragma unroll
            for (int m = 0; m < 2; ++m)
                #pragma unroll
                for (int r = 0; r < 4; ++r) {
                    float a0 = acc[m][0][r], a1 = acc[m][1][r];
                    float a2 = acc[m][2][r], a3 = acc[m][3][r];
                    const float s1 = rowsum16(a0 + a1 + a2 + a3);
                    const float s2 = rowsum16(a0 * a0 + a1 * a1 + a2 * a2 + a3 * a3);
                    const float mu  = s1 * (1.0f / 64.0f);
                    const float var = s2 * (1.0f / 64.0f) - mu * mu;
                    const float inv = rsqrtf(var + LN_EPS);
                    acc[m][0][r] = fmaxf((a0 - mu) * inv * gg[0] + gb[0], 0.f);
                    acc[m][1][r] = fmaxf((a1 - mu) * inv * gg[1] + gb[1], 0.f);
                    acc[m][2][r] = fmaxf((a2 - mu) * inv * gg[2] + gb[2], 0.f);
                    acc[m][3][r] = fmaxf((a3 - mu) * inv * gg[3] + gb[3], 0.f);
                }
        }
        // cs[st] = colsum(y) -> workspace
        #pragma unroll
        for (int n = 0; n < 4; ++n) {
            float p = 0.f;
            #pragma unroll
            for (int m = 0; m < 2; ++m)
                #pragma unroll
                for (int r = 0; r < 4; ++r) p += acc[m][n][r];
            p += __shfl_xor(p, 16);
            p += __shfl_xor(p, 32);
            if (l < 16)
                pooled_ws[(size_t)b * CDIM + st * DIM + n * 16 + l] = p;
        }
    }
}

// ---- classifier: 8 waves (2/SIMD); 3 n-tiles per wave ----
extern "C" __global__ void __launch_bounds__(512)
classifier_kernel(const float* __restrict__ pooled_ws,
                  const unsigned short* __restrict__ wcf,
                  const float* __restrict__ bce, const float* __restrict__ wc2,
                  const float* __restrict__ bc2, float* __restrict__ out)
{
    #define PSTR 196
    __shared__ __align__(16) float P[16 * PSTR];
    __shared__ __align__(16) unsigned int afh[6 * 64 * 4];
    __shared__ __align__(16) unsigned int afl[6 * 64 * 4];
    __shared__ float rsum[8][16];

    const int b = blockIdx.x;
    const int t = threadIdx.x;
    const int l = t & 63;
    const int w = t >> 6;          // 0..7
    const unsigned short* wclo = wcf + 73728;

    for (int i = t; i < 16 * 48; i += 512) {
        const int row = i / 48, q = i % 48;
        const float4 v = ldg4(pooled_ws + ((size_t)(b * 16 + row)) * CDIM + q * 4);
        *reinterpret_cast<float4*>(&P[row * PSTR + q * 4]) = v;
    }
    __syncthreads();

    for (int e = t; e < 6 * 64; e += 512) {
        const int s = e >> 6, ll = e & 63;
        const int row = ll & 15;
        const int k0 = s * 32 + (ll >> 4) * 8;
        const float4 v0 = *reinterpret_cast<const float4*>(&P[row * PSTR + k0]);
        const float4 v1 = *reinterpret_cast<const float4*>(&P[row * PSTR + k0 + 4]);
        const float y[8] = { v0.x, v0.y, v0.z, v0.w, v1.x, v1.y, v1.z, v1.w };
        unsigned int uh[4], ul[4];
        #pragma unroll
        for (int j2 = 0; j2 < 4; ++j2) {
            uh[j2] = pk2(y[j2 * 2], y[j2 * 2 + 1]);
            ul[j2] = pk2lo(y[j2 * 2], y[j2 * 2 + 1], uh[j2]);
        }
        *reinterpret_cast<u32x4*>(&afh[e * 4]) = (u32x4){uh[0], uh[1], uh[2], uh[3]};
        *reinterpret_cast<u32x4*>(&afl[e * 4]) = (u32x4){ul[0], ul[1], ul[2], ul[3]};
    }
    __syncthreads();

    float part[4] = {0.f, 0.f, 0.f, 0.f};
    for (int nt = 0; nt < 3; ++nt) {
        const int n = w * 3 + nt;
        f32x4 acc = {0.f, 0.f, 0.f, 0.f};
        #pragma unroll
        for (int s = 0; s < 6; ++s) {
            const u32x4 ah = *(const u32x4*)&afh[(s * 64 + l) * 4];
            const u32x4 al = *(const u32x4*)&afl[(s * 64 + l) * 4];
            const u32x4 bh = *(const u32x4*)&wcf [((s * 24 + n) * 64 + l) * 8];
            const u32x4 bl = *(const u32x4*)&wclo[((s * 24 + n) * 64 + l) * 8];
            acc = MFMA(ah, bh, acc);
            acc = MFMA(ah, bl, acc);
            acc = MFMA(al, bh, acc);
        }
        const int col = n * 16 + (l & 15);
        const float bias = bce[col], w2 = wc2[col];
        #pragma unroll
        for (int r = 0; r < 4; ++r)
            part[r] += fmaxf(acc[r] + bias, 0.f) * w2;
    }
    #pragma unroll
    for (int r = 0; r < 4; ++r) {
        part[r] += __shfl_xor(part[r], 1);
        part[r] += __shfl_xor(part[r], 2);
        part[r] += __shfl_xor(part[r], 4);
        part[r] += __shfl_xor(part[r], 8);
    }
    if ((l & 15) == 0) {
        const int g = l >> 4;
        #pragma unroll
        for (int r = 0; r < 4; ++r) rsum[w][g * 4 + r] = part[r];
    }
    __syncthreads();
    if (t < 16) {
        float s = bc2[0];
        #pragma unroll
        for (int w2i = 0; w2i < 8; ++w2i) s += rsum[w2i][t];
        out[b * 16 + t] = s;
    }
}

extern "C" void kernel_launch(void* const* d_in, const int* in_sizes, int n_in,
                              void* d_out, int out_size, void* d_ws, size_t ws_size,
                              hipStream_t stream)
{
    const int*   x     = (const int*)d_in[0];
    const int*   los   = (const int*)d_in[1];
    const int*   eidx  = (const int*)d_in[2];
    const float* emb   = (const float*)d_in[3];
    const float* win1  = (const float*)d_in[4];
    const float* bin1  = (const float*)d_in[5];
    const float* gin_g = (const float*)d_in[6];
    const float* gin_b = (const float*)d_in[7];
    const float* win2  = (const float*)d_in[8];
    const float* bin2  = (const float*)d_in[9];
    const float* wh1   = (const float*)d_in[10];
    const float* bh1   = (const float*)d_in[11];
    const float* gh_g  = (const float*)d_in[12];
    const float* gh_b  = (const float*)d_in[13];
    const float* wh2   = (const float*)d_in[14];
    const float* bh2   = (const float*)d_in[15];
    const float* epsv  = (const float*)d_in[16];
    const float* wc1   = (const float*)d_in[17];
    const float* bc1   = (const float*)d_in[18];
    const float* wc2   = (const float*)d_in[19];
    const float* bc2   = (const float*)d_in[20];
    float* out = (float*)d_out;

    unsigned short* wsb = (unsigned short*)((char*)d_ws + WS_WFRAG_OFF);
    float*          b21 = (float*)((char*)d_ws + WS_B21_OFF);
    unsigned short* wcf = (unsigned short*)((char*)d_ws + WS_WCF_OFF);
    float*          bce = (float*)((char*)d_ws + WS_BCE_OFF);
    float*          cs  = (float*)((char*)d_ws + WS_POOL_OFF);
    float*          embw= (float*)((char*)d_ws + WS_EMBW_OFF);

    hipLaunchKernelGGL(prep_w_kernel, dim3(116), dim3(256), 0, stream,
                       win1, win2, wh1, wh2, wc1, bin2, bh2, bc1, emb,
                       wsb, wcf, b21, bce, embw);
    hipLaunchKernelGGL(gin_fused_kernel, dim3(NBATCH / 4), dim3(256), 0, stream,
                       x, los, eidx, (const float*)embw, bin1, gin_g, gin_b,
                       bh1, gh_g, gh_b, epsv,
                       (const unsigned short*)wsb, (const float*)b21, cs);
    hipLaunchKernelGGL(classifier_kernel, dim3(NBATCH / 16), dim3(512), 0, stream,
                       (const float*)cs, (const unsigned short*)wcf,
                       (const float*)bce, wc2, bc2, out);
}